// Round 2
// baseline (690.291 us; speedup 1.0000x reference)
//
#include <hip/hip_runtime.h>
#include <hip/hip_bf16.h>
#include <math.h>

using bf16 = __hip_bfloat16;
typedef __attribute__((ext_vector_type(8))) short bf16x8;
typedef __attribute__((ext_vector_type(4))) float f32x4;

#define B_ 4
#define T_ 2048
#define H_ 1024
#define DI_ 2048
#define BT_ 8192
#define NC_ 16
#define CHUNK_ 128

__device__ __forceinline__ float bf2f(bf16 x) { return __bfloat162float(x); }
__device__ __forceinline__ bf16 f2bf(float x) { return __float2bfloat16(x); }

// ---------------- cast kernels ----------------
__global__ void cast_kernel(const float* __restrict__ in, bf16* __restrict__ out, int n) {
  int i = blockIdx.x * 256 + threadIdx.x;
  int stride = gridDim.x * 256;
  for (; i < n; i += stride) out[i] = f2bf(in[i]);
}

__global__ void cast_pad_kernel(const float* __restrict__ in, bf16* __restrict__ out,
                                int nrow_in, int nrow_out, int ncol) {
  int n = nrow_out * ncol;
  int i = blockIdx.x * 256 + threadIdx.x;
  int stride = gridDim.x * 256;
  for (; i < n; i += stride) {
    int r = i / ncol;
    out[i] = (r < nrow_in) ? f2bf(in[i]) : f2bf(0.f);
  }
}

__global__ void fill_kernel(float* __restrict__ out, float v, int n) {
  int i = blockIdx.x * 256 + threadIdx.x;
  int stride = gridDim.x * 256;
  for (; i < n; i += stride) out[i] = v;
}

// ---------------- bf16 MFMA GEMM, C = A[M,K] * Bw[N,K]^T ----------------
// m97-structure: 128x128 tile, BK=64, 4 waves, global_load_lds width 16.
__device__ __forceinline__ void gload_lds16(const bf16* g, bf16* l) {
  __builtin_amdgcn_global_load_lds((const __attribute__((address_space(1))) void*)(g),
                                   (__attribute__((address_space(3))) void*)(l), 16, 0, 0);
}

template <int EPI>
__global__ __launch_bounds__(256) void gemm_bt(
    const bf16* __restrict__ A, const bf16* __restrict__ Bw, int K, int N,
    float* __restrict__ Cf,                      // EPI 0: fp32 store, ldc = N
    bf16* __restrict__ hid, bf16* __restrict__ shf, bf16* __restrict__ fg)  // EPI 1
{
  __shared__ bf16 As[128 * 64];
  __shared__ bf16 Bs[128 * 64];
  const int tid = threadIdx.x;
  const int lane = tid & 63;
  const int wave = tid >> 6;
  const int bn = blockIdx.x, bm = blockIdx.y;
  const int wr = (wave >> 1) * 64, wc = (wave & 1) * 64;
  f32x4 acc[4][4] = {};
  const int srow = tid >> 3;
  const int scol = (tid & 7) * 8;
  const size_t arow0 = (size_t)bm * 128;
  const size_t brow0 = (size_t)bn * 128;

  for (int kt = 0; kt < K; kt += 64) {
#pragma unroll
    for (int i = 0; i < 4; ++i) {
      const bf16* ga = A + (arow0 + i * 32 + srow) * (size_t)K + kt + scol;
      const bf16* gb = Bw + (brow0 + i * 32 + srow) * (size_t)K + kt + scol;
      gload_lds16(ga, &As[(i * 32 + srow) * 64 + scol]);
      gload_lds16(gb, &Bs[(i * 32 + srow) * 64 + scol]);
    }
    asm volatile("s_waitcnt vmcnt(0)" ::: "memory");
    __syncthreads();
#pragma unroll
    for (int ks = 0; ks < 64; ks += 32) {
      bf16x8 af[4], bfr[4];
#pragma unroll
      for (int i = 0; i < 4; ++i) {
        af[i]  = *(const bf16x8*)&As[(wr + i * 16 + (lane & 15)) * 64 + ks + (lane >> 4) * 8];
        bfr[i] = *(const bf16x8*)&Bs[(wc + i * 16 + (lane & 15)) * 64 + ks + (lane >> 4) * 8];
      }
#pragma unroll
      for (int i = 0; i < 4; ++i)
#pragma unroll
        for (int j = 0; j < 4; ++j)
          acc[i][j] = __builtin_amdgcn_mfma_f32_16x16x32_bf16(af[i], bfr[j], acc[i][j], 0, 0, 0);
    }
    __syncthreads();
  }

  const int crow = wr + (lane >> 4) * 4;
  const int ccol = wc + (lane & 15);
#pragma unroll
  for (int i = 0; i < 4; ++i) {
#pragma unroll
    for (int j = 0; j < 4; ++j) {
#pragma unroll
      for (int r = 0; r < 4; ++r) {
        size_t row = arow0 + crow + i * 16 + r;
        int col = (int)brow0 + ccol + j * 16;
        float v = acc[i][j][r];
        if (EPI == 0) {
          Cf[row * (size_t)N + col] = v;
        } else {
          if (col < DI_) {
            hid[row * DI_ + col] = f2bf(v);
            shf[row * DI_ + col] = f2bf(v / (1.f + expf(-v)));
          } else {
            fg[row * DI_ + (col - DI_)] = f2bf(v);
          }
        }
      }
    }
  }
}

// ---------------- gates: per-row K=64 nonlinearity + k-normalize ----------------
__global__ void gates_kernel(const float* __restrict__ proj,
                             const float* __restrict__ b_g, const float* __restrict__ b_tau,
                             float* __restrict__ qs, float* __restrict__ khat,
                             float* __restrict__ eg, float* __restrict__ gk) {
  int wave = threadIdx.x >> 6;
  int lane = threadIdx.x & 63;
  size_t row = (size_t)blockIdx.x * 4 + wave;
  const float* p = proj + row * 256;
  float q  = p[lane];
  float kk = p[64 + lane];
  float zg = p[128 + lane] + b_g[lane];
  float zt = p[192 + lane] + b_tau[lane];
  float gg = (zg > 20.f) ? zg : log1pf(expf(zg));
  float tau = 1.f / (1.f + expf(-zt));
  float it = powf(gg, tau);
  float gkv = -gg * tau;
  float s = kk * kk;
#pragma unroll
  for (int off = 32; off > 0; off >>= 1) s += __shfl_xor(s, off);
  float kn = sqrtf(s);
  size_t o = row * 64 + lane;
  qs[o] = q * 0.125f;                 // K^-0.5 = 1/8
  khat[o] = kk / fmaxf(kn, 1e-12f) * it;
  eg[o] = expf(gkv);
  gk[o] = gkv;
}

// ---------------- chunk-cumulative decay: qhat2 = qs*exp(gc), Dtot ----------------
__global__ void cumdecay_kernel(const float* __restrict__ gk, const float* __restrict__ qs,
                                float* __restrict__ qhat2, float* __restrict__ Dtot) {
  int g = blockIdx.x * 256 + threadIdx.x;   // 4096 = B*NC*64
  int k = g & 63;
  int c = (g >> 6) & (NC_ - 1);
  int b = g >> 10;
  float gc = 0.f;
  size_t base = ((size_t)(b * T_ + c * CHUNK_)) * 64 + k;
  for (int t = 0; t < CHUNK_; ++t) {
    size_t idx = base + (size_t)t * 64;
    gc += gk[idx];
    qhat2[idx] = qs[idx] * expf(gc);
  }
  Dtot[(b * NC_ + c) * 64 + k] = expf(gc);
}

// ---------------- v = sigmoid(i1 @ w_i2^T + b_i2) * hid ----------------
__global__ __launch_bounds__(256) void vgate_kernel(const bf16* __restrict__ hid,
    const float* __restrict__ i1, const float* __restrict__ w_i2,
    const float* __restrict__ b_i2, bf16* __restrict__ v) {
  __shared__ float s_w2[16 * 256];
  int tid = threadIdx.x;
  int di0 = blockIdx.x * 256;
  int r0 = blockIdx.y * 128;
#pragma unroll
  for (int l = 0; l < 16; ++l)
    s_w2[l * 256 + tid] = w_i2[(size_t)(di0 + tid) * 16 + l];
  __syncthreads();
  float bi = b_i2[di0 + tid];
  for (int rr = 0; rr < 128; ++rr) {
    size_t r = r0 + rr;
    const float* ip = &i1[r * 128];
    float z = bi;
#pragma unroll
    for (int l = 0; l < 16; ++l) z += ip[l] * s_w2[l * 256 + tid];
    float hv = bf2f(hid[r * DI_ + di0 + tid]);
    float ig = 1.f / (1.f + expf(-z));
    v[r * DI_ + di0 + tid] = f2bf(ig * hv);
  }
}

// ---------------- chunk-local scan (h starts at 0 per chunk) ----------------
__global__ __launch_bounds__(256) void scan_kernel(const float* __restrict__ eg,
    const float* __restrict__ khat, const float* __restrict__ qs,
    const bf16* __restrict__ v, float* __restrict__ o, bf16* __restrict__ hloc) {
  __shared__ float s[3 * 8 * 64];
  int tid = threadIdx.x;
  int b = blockIdx.z, c = blockIdx.y;
  int di = blockIdx.x * 256 + tid;
  float h[64];
#pragma unroll
  for (int k = 0; k < 64; ++k) h[k] = 0.f;
  int row0 = b * T_ + c * CHUNK_;
  for (int t0 = 0; t0 < CHUNK_; t0 += 8) {
    size_t base = (size_t)(row0 + t0) * 64;
    __syncthreads();
    for (int i = tid; i < 512; i += 256) {
      s[i] = eg[base + i];
      s[512 + i] = khat[base + i];
      s[1024 + i] = qs[base + i];
    }
    __syncthreads();
    for (int tt = 0; tt < 8; ++tt) {
      size_t row = row0 + t0 + tt;
      float vv = bf2f(v[row * DI_ + di]);
      const float* se = &s[tt * 64];
      const float* sk = &s[512 + tt * 64];
      const float* sq = &s[1024 + tt * 64];
      float oa = 0.f;
#pragma unroll
      for (int k = 0; k < 64; k += 4) {
        float4 e4 = *(const float4*)&se[k];
        float4 k4 = *(const float4*)&sk[k];
        float4 q4 = *(const float4*)&sq[k];
        h[k]     = h[k]     * e4.x + k4.x * vv; oa += q4.x * h[k];
        h[k + 1] = h[k + 1] * e4.y + k4.y * vv; oa += q4.y * h[k + 1];
        h[k + 2] = h[k + 2] * e4.z + k4.z * vv; oa += q4.z * h[k + 2];
        h[k + 3] = h[k + 3] * e4.w + k4.w * vv; oa += q4.w * h[k + 3];
      }
      o[row * DI_ + di] = oa;
    }
  }
  size_t hb = ((size_t)(b * NC_ + c) * 64) * DI_ + di;
#pragma unroll
  for (int k = 0; k < 64; ++k) hloc[hb + (size_t)k * DI_] = f2bf(h[k]);
}

// ---------------- cross-chunk state combine (in-place: hloc -> h_in) ----------------
__global__ void combine_kernel(bf16* __restrict__ h, const float* __restrict__ Dtot) {
  int di = blockIdx.x * 256 + threadIdx.x;
  int k = blockIdx.y;
  int b = blockIdx.z;
  float run = 0.f;
#pragma unroll
  for (int c = 0; c < NC_; ++c) {
    size_t idx = ((size_t)((b * NC_ + c) * 64 + k)) * DI_ + di;
    float t = bf2f(h[idx]);
    h[idx] = f2bf(run);
    run = run * Dtot[(b * NC_ + c) * 64 + k] + t;
  }
}

// ---------------- inter-chunk correction: o += qhat2 @ h_in ----------------
__global__ __launch_bounds__(256) void inter_kernel(const bf16* __restrict__ hin,
    const float* __restrict__ qhat2, float* __restrict__ o) {
  __shared__ float sh[32 * 256];   // 32KB
  int tid = threadIdx.x;
  int di0 = blockIdx.x * 256;
  int c = blockIdx.y, b = blockIdx.z;
  int row0 = b * T_ + c * CHUNK_;
  for (int kh = 0; kh < 2; ++kh) {
    size_t hbase = ((size_t)((b * NC_ + c) * 64 + kh * 32)) * DI_ + di0;
    __syncthreads();
    for (int k = 0; k < 32; ++k)
      sh[k * 256 + tid] = bf2f(hin[hbase + (size_t)k * DI_ + tid]);
    __syncthreads();
    for (int t = 0; t < CHUNK_; ++t) {
      const float* qp = &qhat2[(size_t)(row0 + t) * 64 + kh * 32];
      float acc = 0.f;
#pragma unroll
      for (int k = 0; k < 32; k += 4) {
        float4 q4 = *(const float4*)&qp[k];
        acc += q4.x * sh[(k    ) * 256 + tid];
        acc += q4.y * sh[(k + 1) * 256 + tid];
        acc += q4.z * sh[(k + 2) * 256 + tid];
        acc += q4.w * sh[(k + 3) * 256 + tid];
      }
      size_t oi = (size_t)(row0 + t) * DI_ + di0 + tid;
      o[oi] += acc;
    }
  }
}

// ---------------- residual + gated RMSNorm ----------------
__global__ __launch_bounds__(256) void norm_kernel(const float* __restrict__ o,
    const bf16* __restrict__ shf, const bf16* __restrict__ fg,
    const float* __restrict__ res_w, const float* __restrict__ norm_w,
    bf16* __restrict__ o3) {
  __shared__ float sred[4];
  int tid = threadIdx.x;
  size_t row = blockIdx.x;
  float vals[8];
  float ss = 0.f;
#pragma unroll
  for (int j = 0; j < 8; ++j) {
    int di = tid + j * 256;
    float x2 = o[row * DI_ + di] + bf2f(shf[row * DI_ + di]) * res_w[di];
    vals[j] = x2;
    ss += x2 * x2;
  }
#pragma unroll
  for (int off = 32; off > 0; off >>= 1) ss += __shfl_xor(ss, off);
  if ((tid & 63) == 0) sred[tid >> 6] = ss;
  __syncthreads();
  float tot = sred[0] + sred[1] + sred[2] + sred[3];
  float rinv = rsqrtf(tot / DI_ + 1e-5f);
#pragma unroll
  for (int j = 0; j < 8; ++j) {
    int di = tid + j * 256;
    float fgs = 1.f / (1.f + expf(-bf2f(fg[row * DI_ + di])));
    o3[row * DI_ + di] = f2bf(vals[j] * rinv * norm_w[di] * fgs);
  }
}

// ---------------- host launcher ----------------
// Workspace layout (explicit lifetime-based aliasing), total 200,818,688 B:
//   FRONT region [0 .. 72,876,032): x_bf, wug, wqkgt, wi1p, proj, i1, hid
//     - all dead before scan; obuf (fp32, 67,108,864 B) overlays it from scan on
//     - wdown (bf16, 4,194,304 B) cast into offset 0 AFTER norm (obuf dead)
//   then: vb/o3 (aliased), shf, fgb, hloc(bf16), qs,khat,eg,gk,qhat2, Dtot
extern "C" void kernel_launch(void* const* d_in, const int* in_sizes, int n_in,
                              void* d_out, int out_size, void* d_ws, size_t ws_size,
                              hipStream_t stream) {
  const float* x      = (const float*)d_in[0];
  const float* w_gate = (const float*)d_in[1];
  const float* w_up   = (const float*)d_in[2];
  const float* w_down = (const float*)d_in[3];
  const float* w_q    = (const float*)d_in[4];
  const float* w_k    = (const float*)d_in[5];
  const float* w_g    = (const float*)d_in[6];
  const float* b_g    = (const float*)d_in[7];
  const float* w_tau  = (const float*)d_in[8];
  const float* b_tau  = (const float*)d_in[9];
  const float* w_i1   = (const float*)d_in[10];
  const float* w_i2   = (const float*)d_in[11];
  const float* b_i2   = (const float*)d_in[12];
  const float* norm_w = (const float*)d_in[13];
  const float* res_w  = (const float*)d_in[14];
  float* out = (float*)d_out;

  char* base = (char*)d_ws;
  // front region
  bf16*  x_bf  = (bf16*)(base + 0);                         // 16,777,216
  bf16*  wug   = (bf16*)(base + 16777216);                  //  8,388,608
  bf16*  wqkgt = (bf16*)(base + 25165824);                  //  1,048,576
  bf16*  wi1p  = (bf16*)(base + 26214400);                  //    524,288
  float* proj  = (float*)(base + 26738688);                 //  8,388,608
  float* i1    = (float*)(base + 35127296);                 //  4,194,304
  bf16*  hid   = (bf16*)(base + 39321600);                  // 33,554,432 -> front end 72,876,032
  float* obuf  = (float*)(base + 0);                        // 67,108,864 (overlays front, from scan on)
  bf16*  wdown = (bf16*)(base + 0);                         //  4,194,304 (after norm; obuf dead)
  // persistent region
  bf16*  vb    = (bf16*)(base + 72876032);                  // 33,554,432
  bf16*  o3    = vb;                                        // alias: vb dead after scan, o3 written at norm
  bf16*  shf   = (bf16*)(base + 106430464);                 // 33,554,432
  bf16*  fgb   = (bf16*)(base + 139984896);                 // 33,554,432
  bf16*  hloc  = (bf16*)(base + 173539328);                 // 16,777,216
  float* qs    = (float*)(base + 190316544);                //  2,097,152
  float* khat  = (float*)(base + 192413696);                //  2,097,152
  float* eg    = (float*)(base + 194510848);                //  2,097,152
  float* gk    = (float*)(base + 196608000);                //  2,097,152
  float* qhat2 = (float*)(base + 198705152);                //  2,097,152
  float* Dtot  = (float*)(base + 200802304);                //     16,384
  const size_t TOTAL = 200818688;
  if (ws_size < TOTAL) {
    // diagnostic sentinel: unmistakable error value if workspace is too small
    fill_kernel<<<dim3(512), 256, 0, stream>>>(out, 1.0e6f, out_size);
    return;
  }

  // casts (weights needed early)
  cast_kernel<<<dim3(1024), 256, 0, stream>>>(x, x_bf, BT_ * H_);
  cast_kernel<<<dim3(512), 256, 0, stream>>>(w_up, wug, DI_ * H_);
  cast_kernel<<<dim3(512), 256, 0, stream>>>(w_gate, wug + (size_t)DI_ * H_, DI_ * H_);
  cast_kernel<<<dim3(128), 256, 0, stream>>>(w_q, wqkgt, 64 * DI_);
  cast_kernel<<<dim3(128), 256, 0, stream>>>(w_k, wqkgt + (size_t)64 * DI_, 64 * DI_);
  cast_kernel<<<dim3(128), 256, 0, stream>>>(w_g, wqkgt + (size_t)128 * DI_, 64 * DI_);
  cast_kernel<<<dim3(128), 256, 0, stream>>>(w_tau, wqkgt + (size_t)192 * DI_, 64 * DI_);
  cast_pad_kernel<<<dim3(256), 256, 0, stream>>>(w_i1, wi1p, 16, 128, DI_);

  // up/gate projection + SiLU  (N = 4096: cols<2048 -> hid/shift, else fg)
  gemm_bt<1><<<dim3(32, 64), 256, 0, stream>>>(x_bf, wug, H_, 4096, nullptr, hid, shf, fgb);
  // q,k,g,tau projection from shift
  gemm_bt<0><<<dim3(2, 64), 256, 0, stream>>>(shf, wqkgt, DI_, 256, proj, nullptr, nullptr, nullptr);
  // i1 = hid @ w_i1^T (padded N=128)
  gemm_bt<0><<<dim3(1, 64), 256, 0, stream>>>(hid, wi1p, DI_, 128, i1, nullptr, nullptr, nullptr);

  gates_kernel<<<dim3(2048), 256, 0, stream>>>(proj, b_g, b_tau, qs, khat, eg, gk);
  cumdecay_kernel<<<dim3(16), 256, 0, stream>>>(gk, qs, qhat2, Dtot);
  vgate_kernel<<<dim3(8, 64), 256, 0, stream>>>(hid, i1, w_i2, b_i2, vb);
  // NOTE: hid, i1, proj, x_bf, wug, wqkgt, wi1p all dead past this point -> obuf may overlay

  scan_kernel<<<dim3(8, NC_, B_), 256, 0, stream>>>(eg, khat, qs, vb, obuf, hloc);
  combine_kernel<<<dim3(8, 64, B_), 256, 0, stream>>>(hloc, Dtot);
  inter_kernel<<<dim3(8, NC_, B_), 256, 0, stream>>>(hloc, qhat2, obuf);

  norm_kernel<<<dim3(BT_), 256, 0, stream>>>(obuf, shf, fgb, res_w, norm_w, o3);
  // obuf dead -> cast w_down into front region, then down projection -> d_out
  cast_kernel<<<dim3(512), 256, 0, stream>>>(w_down, wdown, H_ * DI_);
  gemm_bt<0><<<dim3(8, 64), 256, 0, stream>>>(o3, wdown, DI_, 1024, out, nullptr, nullptr, nullptr);
}

// Round 3
// 676.364 us; speedup vs baseline: 1.0206x; 1.0206x over previous
//
#include <hip/hip_runtime.h>
#include <hip/hip_bf16.h>
#include <math.h>

using bf16 = __hip_bfloat16;
typedef __attribute__((ext_vector_type(8))) short bf16x8;
typedef __attribute__((ext_vector_type(4))) float f32x4;

#define B_ 4
#define T_ 2048
#define H_ 1024
#define DI_ 2048
#define BT_ 8192
#define NC_ 16
#define CHUNK_ 128

__device__ __forceinline__ float bf2f(bf16 x) { return __bfloat162float(x); }
__device__ __forceinline__ bf16 f2bf(float x) { return __float2bfloat16(x); }
__device__ __forceinline__ f32x4 mfma16(bf16x8 a, bf16x8 b, f32x4 c) {
  return __builtin_amdgcn_mfma_f32_16x16x32_bf16(a, b, c, 0, 0, 0);
}
__device__ __forceinline__ void gload_lds16(const bf16* g, bf16* l) {
  __builtin_amdgcn_global_load_lds((const __attribute__((address_space(1))) void*)(g),
                                   (__attribute__((address_space(3))) void*)(l), 16, 0, 0);
}

// ---------------- cast kernels ----------------
__global__ void cast_kernel(const float* __restrict__ in, bf16* __restrict__ out, int n) {
  int i = blockIdx.x * 256 + threadIdx.x;
  int stride = gridDim.x * 256;
  for (; i < n; i += stride) out[i] = f2bf(in[i]);
}

struct bf16q { bf16 a, b, c, d; };
__device__ __forceinline__ void cast4(const float* __restrict__ src, bf16* __restrict__ dst, int q) {
  float4 v = *(const float4*)(src + (size_t)q * 4);
  bf16q t = { f2bf(v.x), f2bf(v.y), f2bf(v.z), f2bf(v.w) };
  *(bf16q*)(dst + (size_t)q * 4) = t;
}

// one kernel casts all fp32 weights/activations needed before the scan
__global__ void fused_cast_kernel(const float* __restrict__ x, const float* __restrict__ w_up,
                                  const float* __restrict__ w_gate, const float* __restrict__ w_q,
                                  const float* __restrict__ w_k, const float* __restrict__ w_g,
                                  const float* __restrict__ w_tau, const float* __restrict__ w_i1,
                                  bf16* __restrict__ x_bf, bf16* __restrict__ wug,
                                  bf16* __restrict__ wqkgt, bf16* __restrict__ wi1p) {
  // quad-granular segments
  const int B0 = 0;            // x: 2097152 quads
  const int B1 = 2097152;      // w_up: 524288
  const int B2 = 2621440;      // w_gate: 524288
  const int B3 = 3145728;      // w_q: 32768
  const int B4 = 3178496;      // w_k
  const int B5 = 3211264;      // w_g
  const int B6 = 3244032;      // w_tau
  const int B7 = 3276800;      // wi1p: 65536 (first 8192 from w_i1, rest zero)
  const int END = 3342336;
  int i = blockIdx.x * 256 + threadIdx.x;
  int stride = gridDim.x * 256;
  for (; i < END; i += stride) {
    if (i < B1)      cast4(x,      x_bf,                i - B0);
    else if (i < B2) cast4(w_up,   wug,                 i - B1);
    else if (i < B3) cast4(w_gate, wug + 2097152,       i - B2);
    else if (i < B4) cast4(w_q,    wqkgt,               i - B3);
    else if (i < B5) cast4(w_k,    wqkgt + 131072,      i - B4);
    else if (i < B6) cast4(w_g,    wqkgt + 262144,      i - B5);
    else if (i < B7) cast4(w_tau,  wqkgt + 393216,      i - B6);
    else {
      int q = i - B7;
      if (q < 8192) cast4(w_i1, wi1p, q);
      else { bf16q z = { f2bf(0.f), f2bf(0.f), f2bf(0.f), f2bf(0.f) }; *(bf16q*)(wi1p + (size_t)q * 4) = z; }
    }
  }
}

__global__ void fill_kernel(float* __restrict__ out, float v, int n) {
  int i = blockIdx.x * 256 + threadIdx.x;
  int stride = gridDim.x * 256;
  for (; i < n; i += stride) out[i] = v;
}

// ============ 256x256-tile 8-phase bf16 GEMM (T1+T2+T3+T4+T5) ============
// C = A[M,K] * Bw[N,K]^T. 512 threads = 8 waves (2Mx4N), per-wave out 128x64.
// LDS 128KB dynamic: As[2][256][64] bf16, Bs[2][256][64].
//   A rows laid out as [mh][rw][64] (mh = quadrant-half), B rows as [nh][wc][32].
//   st_16x32 swizzle: phys_byte = lin_byte ^ (((lin_byte>>9)&1)<<5); applied via
//   pre-swizzled GLOBAL source (linear global_load_lds dest) + swizzled ds_read.
// Stage schedule per K-tile t (cur=t&1): ph1: A-h1(t+1)->nxt, ph2: B-h1(t+1)->nxt,
//   ph3: A-h0(t+2)->cur (region dead after ph1), ph4: B-h0(t+2)->cur (dead after ph1).
//   vmcnt(4) at ph4 => tile t+1 fully landed, 2 halves in flight.
template <int EPI>
__global__ __launch_bounds__(512) void gemm256(
    const bf16* __restrict__ A, const bf16* __restrict__ Bw, int K, int N, int NBN,
    float* __restrict__ Cf, bf16* __restrict__ hid, bf16* __restrict__ shf, bf16* __restrict__ fg) {
  extern __shared__ bf16 lds[];
  bf16* As = lds;            // + buf*16384 elems
  bf16* Bs = lds + 32768;
  const int tid = threadIdx.x;
  const int lane = tid & 63;
  const int wv = tid >> 6;
  const int wr = wv >> 2;    // 0..1
  const int wc = wv & 3;     // 0..3
  // XCD-aware swizzle (grid % 8 == 0)
  const int cpx = gridDim.x >> 3;
  const int bid = blockIdx.x;
  const int swz = (bid & 7) * cpx + (bid >> 3);
  const int bm = swz / NBN, bn = swz % NBN;
  const size_t arow0 = (size_t)bm * 256;
  const size_t brow0 = (size_t)bn * 256;

  // precomputed staging sources (pre-swizzled) and linear LDS dests
  const bf16* gA[2][2]; const bf16* gB[2][2];
  int loff[2][2];
#pragma unroll
  for (int h = 0; h < 2; ++h)
#pragma unroll
    for (int j = 0; j < 2; ++j) {
      int D = h * 16384 + (j * 512 + tid) * 16;          // phys byte in 32KB buf
      int L = D ^ (((D >> 9) & 1) << 5);                  // logical byte
      int lrow = L >> 7;
      int col = (L & 127) >> 1;
      int arow = ((lrow >> 6) & 1) * 128 + h * 64 + (lrow & 63);
      int lrl = lrow & 127;
      int brow = (lrl >> 5) * 64 + h * 32 + (lrl & 31);
      gA[h][j] = A + (arow0 + arow) * (size_t)K + col;
      gB[h][j] = Bw + (brow0 + brow) * (size_t)K + col;
      loff[h][j] = D >> 1;                                // elems
    }
#define STAGE_A(buf, h, kt) { gload_lds16(gA[h][0] + (kt), As + (buf) * 16384 + loff[h][0]); \
                              gload_lds16(gA[h][1] + (kt), As + (buf) * 16384 + loff[h][1]); }
#define STAGE_B(buf, h, kt) { gload_lds16(gB[h][0] + (kt), Bs + (buf) * 16384 + loff[h][0]); \
                              gload_lds16(gB[h][1] + (kt), Bs + (buf) * 16384 + loff[h][1]); }

  // swizzled ds_read of one MFMA fragment
  auto lda = [&](int buf, int mh, int mi, int ks) -> bf16x8 {
    int lrow = (mh * 2 + wr) * 64 + mi * 16 + (lane & 15);
    int byte = lrow * 128 + ks * 64 + (lane >> 4) * 16;
    byte ^= ((byte >> 9) & 1) << 5;
    return *(const bf16x8*)&As[buf * 16384 + (byte >> 1)];
  };
  auto ldb = [&](int buf, int nh, int ni, int ks) -> bf16x8 {
    int lrow = (nh * 4 + wc) * 32 + ni * 16 + (lane & 15);
    int byte = lrow * 128 + ks * 64 + (lane >> 4) * 16;
    byte ^= ((byte >> 9) & 1) << 5;
    return *(const bf16x8*)&Bs[buf * 16384 + (byte >> 1)];
  };

  f32x4 acc[8][4] = {};
  const int NT = K >> 6;
  // prologue: tile0 (4 halves) + tile1 h0 halves
  STAGE_A(0, 0, 0); STAGE_B(0, 0, 0); STAGE_A(0, 1, 0); STAGE_B(0, 1, 0);
  if (NT > 1) { STAGE_A(1, 0, 64); STAGE_B(1, 0, 64); }
  asm volatile("s_waitcnt vmcnt(4)" ::: "memory");
  __syncthreads();

  for (int t = 0; t < NT; ++t) {
    const int cur = t & 1, nxt = cur ^ 1;
    const int kt1 = (t + 1) << 6, kt2 = (t + 2) << 6;
    bf16x8 a0[4][2], a1[4][2], b0[2][2], b1[2][2];
    // ---- phase 1: Q(mh0, nh0) ----
#pragma unroll
    for (int mi = 0; mi < 4; ++mi) { a0[mi][0] = lda(cur, 0, mi, 0); a0[mi][1] = lda(cur, 0, mi, 1); }
#pragma unroll
    for (int ni = 0; ni < 2; ++ni) { b0[ni][0] = ldb(cur, 0, ni, 0); b0[ni][1] = ldb(cur, 0, ni, 1); }
    if (t + 1 < NT) STAGE_A(nxt, 1, kt1);
    __builtin_amdgcn_s_barrier();
    asm volatile("s_waitcnt lgkmcnt(0)" ::: "memory");
    __builtin_amdgcn_sched_barrier(0);
    __builtin_amdgcn_s_setprio(1);
#pragma unroll
    for (int mi = 0; mi < 4; ++mi)
#pragma unroll
      for (int ni = 0; ni < 2; ++ni) {
        acc[mi][ni] = mfma16(a0[mi][0], b0[ni][0], acc[mi][ni]);
        acc[mi][ni] = mfma16(a0[mi][1], b0[ni][1], acc[mi][ni]);
      }
    __builtin_amdgcn_s_setprio(0);
    __builtin_amdgcn_s_barrier();
    // ---- phase 2: Q(mh0, nh1) ----
#pragma unroll
    for (int ni = 0; ni < 2; ++ni) { b1[ni][0] = ldb(cur, 1, ni, 0); b1[ni][1] = ldb(cur, 1, ni, 1); }
    if (t + 1 < NT) STAGE_B(nxt, 1, kt1);
    __builtin_amdgcn_s_barrier();
    asm volatile("s_waitcnt lgkmcnt(0)" ::: "memory");
    __builtin_amdgcn_sched_barrier(0);
    __builtin_amdgcn_s_setprio(1);
#pragma unroll
    for (int mi = 0; mi < 4; ++mi)
#pragma unroll
      for (int ni = 0; ni < 2; ++ni) {
        acc[mi][2 + ni] = mfma16(a0[mi][0], b1[ni][0], acc[mi][2 + ni]);
        acc[mi][2 + ni] = mfma16(a0[mi][1], b1[ni][1], acc[mi][2 + ni]);
      }
    __builtin_amdgcn_s_setprio(0);
    __builtin_amdgcn_s_barrier();
    // ---- phase 3: Q(mh1, nh0) ----  (b0 reused from registers)
#pragma unroll
    for (int mi = 0; mi < 4; ++mi) { a1[mi][0] = lda(cur, 1, mi, 0); a1[mi][1] = lda(cur, 1, mi, 1); }
    if (t + 2 < NT) STAGE_A(cur, 0, kt2);
    __builtin_amdgcn_s_barrier();
    asm volatile("s_waitcnt lgkmcnt(0)" ::: "memory");
    __builtin_amdgcn_sched_barrier(0);
    __builtin_amdgcn_s_setprio(1);
#pragma unroll
    for (int mi = 0; mi < 4; ++mi)
#pragma unroll
      for (int ni = 0; ni < 2; ++ni) {
        acc[4 + mi][ni] = mfma16(a1[mi][0], b0[ni][0], acc[4 + mi][ni]);
        acc[4 + mi][ni] = mfma16(a1[mi][1], b0[ni][1], acc[4 + mi][ni]);
      }
    __builtin_amdgcn_s_setprio(0);
    __builtin_amdgcn_s_barrier();
    // ---- phase 4: Q(mh1, nh1) ----  (a1, b1 reused; no ds_read)
    if (t + 2 < NT) STAGE_B(cur, 0, kt2);
    __builtin_amdgcn_s_barrier();
    __builtin_amdgcn_s_setprio(1);
#pragma unroll
    for (int mi = 0; mi < 4; ++mi)
#pragma unroll
      for (int ni = 0; ni < 2; ++ni) {
        acc[4 + mi][2 + ni] = mfma16(a1[mi][0], b1[ni][0], acc[4 + mi][2 + ni]);
        acc[4 + mi][2 + ni] = mfma16(a1[mi][1], b1[ni][1], acc[4 + mi][2 + ni]);
      }
    __builtin_amdgcn_s_setprio(0);
    if (t < NT - 2) { asm volatile("s_waitcnt vmcnt(4)" ::: "memory"); }
    else            { asm volatile("s_waitcnt vmcnt(0)" ::: "memory"); }
    __builtin_amdgcn_s_barrier();
  }

  // epilogue
  const int r0 = wr * 128 + (lane >> 4) * 4;
  const int c0 = wc * 64 + (lane & 15);
#pragma unroll
  for (int mi = 0; mi < 8; ++mi)
#pragma unroll
    for (int ni = 0; ni < 4; ++ni)
#pragma unroll
      for (int r = 0; r < 4; ++r) {
        size_t row = arow0 + r0 + mi * 16 + r;
        int col = (int)brow0 + c0 + ni * 16;
        float v = acc[mi][ni][r];
        if (EPI == 0) {
          Cf[row * (size_t)N + col] = v;
        } else {
          if (col < DI_) {
            hid[row * DI_ + col] = f2bf(v);
            shf[row * DI_ + col] = f2bf(v / (1.f + expf(-v)));
          } else {
            fg[row * DI_ + (col - DI_)] = f2bf(v);
          }
        }
      }
#undef STAGE_A
#undef STAGE_B
}

// ---------------- 2-phase 128x128 GEMM with optional split-K atomic epilogue ----------------
template <int ATOMIC>
__global__ __launch_bounds__(256) void gemm_bt(
    const bf16* __restrict__ A, const bf16* __restrict__ Bw, int K, int N, int kchunk,
    float* __restrict__ Cf) {
  __shared__ bf16 As[128 * 64];
  __shared__ bf16 Bs[128 * 64];
  const int tid = threadIdx.x;
  const int lane = tid & 63;
  const int wave = tid >> 6;
  const int bn = blockIdx.x, bm = blockIdx.y;
  const int wr = (wave >> 1) * 64, wc = (wave & 1) * 64;
  f32x4 acc[4][4] = {};
  const int srow = tid >> 3;
  const int scol = (tid & 7) * 8;
  const size_t arow0 = (size_t)bm * 128;
  const size_t brow0 = (size_t)bn * 128;
  const int k0 = blockIdx.z * kchunk;

  for (int kt = k0; kt < k0 + kchunk; kt += 64) {
#pragma unroll
    for (int i = 0; i < 4; ++i) {
      const bf16* ga = A + (arow0 + i * 32 + srow) * (size_t)K + kt + scol;
      const bf16* gb = Bw + (brow0 + i * 32 + srow) * (size_t)K + kt + scol;
      gload_lds16(ga, &As[(i * 32 + srow) * 64 + scol]);
      gload_lds16(gb, &Bs[(i * 32 + srow) * 64 + scol]);
    }
    asm volatile("s_waitcnt vmcnt(0)" ::: "memory");
    __syncthreads();
#pragma unroll
    for (int ks = 0; ks < 64; ks += 32) {
      bf16x8 af[4], bfr[4];
#pragma unroll
      for (int i = 0; i < 4; ++i) {
        af[i]  = *(const bf16x8*)&As[(wr + i * 16 + (lane & 15)) * 64 + ks + (lane >> 4) * 8];
        bfr[i] = *(const bf16x8*)&Bs[(wc + i * 16 + (lane & 15)) * 64 + ks + (lane >> 4) * 8];
      }
#pragma unroll
      for (int i = 0; i < 4; ++i)
#pragma unroll
        for (int j = 0; j < 4; ++j)
          acc[i][j] = mfma16(af[i], bfr[j], acc[i][j]);
    }
    __syncthreads();
  }

  const int crow = wr + (lane >> 4) * 4;
  const int ccol = wc + (lane & 15);
#pragma unroll
  for (int i = 0; i < 4; ++i)
#pragma unroll
    for (int j = 0; j < 4; ++j)
#pragma unroll
      for (int r = 0; r < 4; ++r) {
        size_t row = arow0 + crow + i * 16 + r;
        int col = (int)brow0 + ccol + j * 16;
        float v = acc[i][j][r];
        if (ATOMIC) atomicAdd(&Cf[row * (size_t)N + col], v);
        else Cf[row * (size_t)N + col] = v;
      }
}

// ---------------- fused gates + chunk-cumsum ----------------
// block = one (b, chunk): 64 blocks x 256 threads
__global__ __launch_bounds__(256) void gates_cum_kernel(const float* __restrict__ proj,
    const float* __restrict__ b_g, const float* __restrict__ b_tau,
    float* __restrict__ qs, float* __restrict__ khat, float* __restrict__ eg,
    float* __restrict__ qhat2, float* __restrict__ Dtot) {
  __shared__ float s_gk[128 * 64];   // 32KB
  __shared__ float segsum[4 * 64];
  int tid = threadIdx.x;
  int lane = tid & 63;
  int wvv = tid >> 6;
  int bc = blockIdx.x;
  size_t row0 = (size_t)((bc >> 4) * T_ + (bc & 15) * CHUNK_);
  // phase A: gates nonlinearity; wave w handles rows w, w+4, ...
  for (int r = wvv; r < 128; r += 4) {
    const float* p = proj + (row0 + r) * 256;
    float q  = p[lane];
    float kk = p[64 + lane];
    float zg = p[128 + lane] + b_g[lane];
    float zt = p[192 + lane] + b_tau[lane];
    float gg  = (zg > 20.f) ? zg : log1pf(expf(zg));
    float tau = 1.f / (1.f + expf(-zt));
    float it  = powf(gg, tau);
    float gkv = -gg * tau;
    float s = kk * kk;
#pragma unroll
    for (int off = 32; off > 0; off >>= 1) s += __shfl_xor(s, off);
    float kn = sqrtf(s);
    size_t o = (row0 + r) * 64 + lane;
    qs[o]   = q * 0.125f;
    khat[o] = kk / fmaxf(kn, 1e-12f) * it;
    eg[o]   = expf(gkv);
    s_gk[r * 64 + lane] = gkv;
  }
  __syncthreads();
  // phase B: segmented cumsum over t; thread (k=lane, seg=wvv): rows seg*32..+31
  float loc = 0.f;
  for (int r = wvv * 32; r < wvv * 32 + 32; ++r) loc += s_gk[r * 64 + lane];
  segsum[wvv * 64 + lane] = loc;
  __syncthreads();
  float gc = 0.f;
  for (int ss = 0; ss < wvv; ++ss) gc += segsum[ss * 64 + lane];
  for (int r = wvv * 32; r < wvv * 32 + 32; ++r) {
    gc += s_gk[r * 64 + lane];
    float qv = proj[(row0 + r) * 256 + lane] * 0.125f;
    qhat2[(row0 + r) * 64 + lane] = qv * expf(gc);
  }
  if (wvv == 3) Dtot[bc * 64 + lane] = expf(gc);
}

// ---------------- v = sigmoid(i1 @ w_i2^T + b_i2) * hid ----------------
__global__ __launch_bounds__(256) void vgate_kernel(const bf16* __restrict__ hid,
    const float* __restrict__ i1, const float* __restrict__ w_i2,
    const float* __restrict__ b_i2, bf16* __restrict__ v) {
  __shared__ float s_w2[16 * 256];
  int tid = threadIdx.x;
  int di0 = blockIdx.x * 256;
  int r0 = blockIdx.y * 128;
#pragma unroll
  for (int l = 0; l < 16; ++l)
    s_w2[l * 256 + tid] = w_i2[(size_t)(di0 + tid) * 16 + l];
  __syncthreads();
  float bi = b_i2[di0 + tid];
  for (int rr = 0; rr < 128; ++rr) {
    size_t r = r0 + rr;
    const float* ip = &i1[r * 128];
    float z = bi;
#pragma unroll
    for (int l = 0; l < 16; ++l) z += ip[l] * s_w2[l * 256 + tid];
    float hv = bf2f(hid[r * DI_ + di0 + tid]);
    float ig = 1.f / (1.f + expf(-z));
    v[r * DI_ + di0 + tid] = f2bf(ig * hv);
  }
}

// ---------------- chunk-local scan ----------------
__global__ __launch_bounds__(256) void scan_kernel(const float* __restrict__ eg,
    const float* __restrict__ khat, const float* __restrict__ qs,
    const bf16* __restrict__ v, float* __restrict__ o, bf16* __restrict__ hloc) {
  __shared__ float s[3 * 8 * 64];
  int tid = threadIdx.x;
  int b = blockIdx.z, c = blockIdx.y;
  int di = blockIdx.x * 256 + tid;
  float h[64];
#pragma unroll
  for (int k = 0; k < 64; ++k) h[k] = 0.f;
  int row0 = b * T_ + c * CHUNK_;
  for (int t0 = 0; t0 < CHUNK_; t0 += 8) {
    size_t base = (size_t)(row0 + t0) * 64;
    __syncthreads();
    for (int i = tid; i < 512; i += 256) {
      s[i] = eg[base + i];
      s[512 + i] = khat[base + i];
      s[1024 + i] = qs[base + i];
    }
    __syncthreads();
    for (int tt = 0; tt < 8; ++tt) {
      size_t row = row0 + t0 + tt;
      float vv = bf2f(v[row * DI_ + di]);
      const float* se = &s[tt * 64];
      const float* sk = &s[512 + tt * 64];
      const float* sq = &s[1024 + tt * 64];
      float oa = 0.f;
#pragma unroll
      for (int k = 0; k < 64; k += 4) {
        float4 e4 = *(const float4*)&se[k];
        float4 k4 = *(const float4*)&sk[k];
        float4 q4 = *(const float4*)&sq[k];
        h[k]     = h[k]     * e4.x + k4.x * vv; oa += q4.x * h[k];
        h[k + 1] = h[k + 1] * e4.y + k4.y * vv; oa += q4.y * h[k + 1];
        h[k + 2] = h[k + 2] * e4.z + k4.z * vv; oa += q4.z * h[k + 2];
        h[k + 3] = h[k + 3] * e4.w + k4.w * vv; oa += q4.w * h[k + 3];
      }
      o[row * DI_ + di] = oa;
    }
  }
  size_t hb = ((size_t)(b * NC_ + c) * 64) * DI_ + di;
#pragma unroll
  for (int k = 0; k < 64; ++k) hloc[hb + (size_t)k * DI_] = f2bf(h[k]);
}

// ---------------- cross-chunk state combine ----------------
__global__ void combine_kernel(bf16* __restrict__ h, const float* __restrict__ Dtot) {
  int di = blockIdx.x * 256 + threadIdx.x;
  int k = blockIdx.y;
  int b = blockIdx.z;
  float run = 0.f;
#pragma unroll
  for (int c = 0; c < NC_; ++c) {
    size_t idx = ((size_t)((b * NC_ + c) * 64 + k)) * DI_ + di;
    float t = bf2f(h[idx]);
    h[idx] = f2bf(run);
    run = run * Dtot[(b * NC_ + c) * 64 + k] + t;
  }
}

// ---------------- inter-chunk correction: o += qhat2 @ h_in ----------------
__global__ __launch_bounds__(256) void inter_kernel(const bf16* __restrict__ hin,
    const float* __restrict__ qhat2, float* __restrict__ o) {
  __shared__ float sh[32 * 256];   // 32KB
  int tid = threadIdx.x;
  int di0 = blockIdx.x * 256;
  int c = blockIdx.y, b = blockIdx.z;
  int row0 = b * T_ + c * CHUNK_;
  for (int kh = 0; kh < 2; ++kh) {
    size_t hbase = ((size_t)((b * NC_ + c) * 64 + kh * 32)) * DI_ + di0;
    __syncthreads();
    for (int k = 0; k < 32; ++k)
      sh[k * 256 + tid] = bf2f(hin[hbase + (size_t)k * DI_ + tid]);
    __syncthreads();
    for (int t = 0; t < CHUNK_; ++t) {
      const float* qp = &qhat2[(size_t)(row0 + t) * 64 + kh * 32];
      float acc = 0.f;
#pragma unroll
      for (int k = 0; k < 32; k += 4) {
        float4 q4 = *(const float4*)&qp[k];
        acc += q4.x * sh[(k    ) * 256 + tid];
        acc += q4.y * sh[(k + 1) * 256 + tid];
        acc += q4.z * sh[(k + 2) * 256 + tid];
        acc += q4.w * sh[(k + 3) * 256 + tid];
      }
      size_t oi = (size_t)(row0 + t) * DI_ + di0 + tid;
      o[oi] += acc;
    }
  }
}

// ---------------- residual + gated RMSNorm ----------------
__global__ __launch_bounds__(256) void norm_kernel(const float* __restrict__ o,
    const bf16* __restrict__ shf, const bf16* __restrict__ fg,
    const float* __restrict__ res_w, const float* __restrict__ norm_w,
    bf16* __restrict__ o3) {
  __shared__ float sred[4];
  int tid = threadIdx.x;
  size_t row = blockIdx.x;
  float vals[8];
  float ss = 0.f;
#pragma unroll
  for (int j = 0; j < 8; ++j) {
    int di = tid + j * 256;
    float x2 = o[row * DI_ + di] + bf2f(shf[row * DI_ + di]) * res_w[di];
    vals[j] = x2;
    ss += x2 * x2;
  }
#pragma unroll
  for (int off = 32; off > 0; off >>= 1) ss += __shfl_xor(ss, off);
  if ((tid & 63) == 0) sred[tid >> 6] = ss;
  __syncthreads();
  float tot = sred[0] + sred[1] + sred[2] + sred[3];
  float rinv = rsqrtf(tot / DI_ + 1e-5f);
#pragma unroll
  for (int j = 0; j < 8; ++j) {
    int di = tid + j * 256;
    float fgs = 1.f / (1.f + expf(-bf2f(fg[row * DI_ + di])));
    o3[row * DI_ + di] = f2bf(vals[j] * rinv * norm_w[di] * fgs);
  }
}

// ---------------- host launcher ----------------
extern "C" void kernel_launch(void* const* d_in, const int* in_sizes, int n_in,
                              void* d_out, int out_size, void* d_ws, size_t ws_size,
                              hipStream_t stream) {
  const float* x      = (const float*)d_in[0];
  const float* w_gate = (const float*)d_in[1];
  const float* w_up   = (const float*)d_in[2];
  const float* w_down = (const float*)d_in[3];
  const float* w_q    = (const float*)d_in[4];
  const float* w_k    = (const float*)d_in[5];
  const float* w_g    = (const float*)d_in[6];
  const float* b_g    = (const float*)d_in[7];
  const float* w_tau  = (const float*)d_in[8];
  const float* b_tau  = (const float*)d_in[9];
  const float* w_i1   = (const float*)d_in[10];
  const float* w_i2   = (const float*)d_in[11];
  const float* b_i2   = (const float*)d_in[12];
  const float* norm_w = (const float*)d_in[13];
  const float* res_w  = (const float*)d_in[14];
  float* out = (float*)d_out;

  char* base = (char*)d_ws;
  // front region (dead before scan; obuf overlays it from scan on)
  bf16*  x_bf  = (bf16*)(base + 0);                         // 16,777,216
  bf16*  wug   = (bf16*)(base + 16777216);                  //  8,388,608
  bf16*  wqkgt = (bf16*)(base + 25165824);                  //  1,048,576
  bf16*  wi1p  = (bf16*)(base + 26214400);                  //    524,288
  float* proj  = (float*)(base + 26738688);                 //  8,388,608
  float* i1    = (float*)(base + 35127296);                 //  4,194,304
  bf16*  hid   = (bf16*)(base + 39321600);                  // 33,554,432 -> front end 72,876,032
  float* obuf  = (float*)(base + 0);                        // 67,108,864 overlay
  // persistent region
  bf16*  vb    = (bf16*)(base + 72876032);                  // 33,554,432
  bf16*  o3    = vb;                                        // vb dead after scan
  bf16*  shf   = (bf16*)(base + 106430464);                 // 33,554,432
  bf16*  fgb   = (bf16*)(base + 139984896);                 // 33,554,432
  bf16*  hloc  = (bf16*)(base + 173539328);                 // 16,777,216
  bf16*  wdown = (bf16*)(base + 173539328);                 //  4,194,304 (after inter; hloc dead)
  float* qs    = (float*)(base + 190316544);                //  2,097,152
  float* khat  = (float*)(base + 192413696);                //  2,097,152
  float* eg    = (float*)(base + 194510848);                //  2,097,152
  float* gk    = (float*)(base + 196608000);                //  2,097,152 (unused, kept for layout)
  float* qhat2 = (float*)(base + 198705152);                //  2,097,152
  float* Dtot  = (float*)(base + 200802304);                //     16,384
  (void)gk;
  const size_t TOTAL = 200818688;
  if (ws_size < TOTAL) {
    fill_kernel<<<dim3(512), 256, 0, stream>>>(out, 1.0e6f, out_size);
    return;
  }

  // opt-in to 128KB dynamic LDS (idempotent host-side call; capture-safe)
  hipFuncSetAttribute((const void*)gemm256<1>, hipFuncAttributeMaxDynamicSharedMemorySize, 131072);
  hipFuncSetAttribute((const void*)gemm256<0>, hipFuncAttributeMaxDynamicSharedMemorySize, 131072);

  // zero split-K accumulators
  hipMemsetAsync(proj, 0, (size_t)BT_ * 256 * 4, stream);
  hipMemsetAsync(i1, 0, (size_t)BT_ * 128 * 4, stream);

  // all pre-scan casts in one kernel
  fused_cast_kernel<<<dim3(2048), 256, 0, stream>>>(x, w_up, w_gate, w_q, w_k, w_g, w_tau, w_i1,
                                                    x_bf, wug, wqkgt, wi1p);

  // GEMM1: [hid|fg] = x @ [w_up;w_gate]^T, + SiLU  (8-phase 256^2, grid 32x16=512)
  gemm256<1><<<dim3(512), 512, 131072, stream>>>(x_bf, wug, H_, 4096, 16, nullptr, hid, shf, fgb);
  // GEMM2: proj = shf @ [wq;wk;wg;wtau]^T  (split-K x4, atomic)
  gemm_bt<1><<<dim3(2, 64, 4), 256, 0, stream>>>(shf, wqkgt, DI_, 256, 512, proj);
  // GEMM3: i1 = hid @ w_i1p^T  (split-K x8, atomic)
  gemm_bt<1><<<dim3(1, 64, 8), 256, 0, stream>>>(hid, wi1p, DI_, 128, 256, i1);

  gates_cum_kernel<<<dim3(64), 256, 0, stream>>>(proj, b_g, b_tau, qs, khat, eg, qhat2, Dtot);
  vgate_kernel<<<dim3(8, 64), 256, 0, stream>>>(hid, i1, w_i2, b_i2, vb);
  // front region dead -> obuf overlay valid from here

  scan_kernel<<<dim3(8, NC_, B_), 256, 0, stream>>>(eg, khat, qs, vb, obuf, hloc);
  combine_kernel<<<dim3(8, 64, B_), 256, 0, stream>>>(hloc, Dtot);
  inter_kernel<<<dim3(8, NC_, B_), 256, 0, stream>>>(hloc, qhat2, obuf);

  // hloc dead -> cast w_down into its region (overlaps with norm)
  cast_kernel<<<dim3(512), 256, 0, stream>>>(w_down, wdown, H_ * DI_);
  norm_kernel<<<dim3(BT_), 256, 0, stream>>>(obuf, shf, fgb, res_w, norm_w, o3);
  // GEMM4: out = o3 @ w_down^T  (8-phase 256^2, grid 32x4=128)
  gemm256<0><<<dim3(128), 512, 131072, stream>>>(o3, wdown, DI_, H_, 4, out, nullptr, nullptr, nullptr);
}

// Round 4
// 600.710 us; speedup vs baseline: 1.1491x; 1.1259x over previous
//
#include <hip/hip_runtime.h>
#include <hip/hip_bf16.h>
#include <math.h>

using bf16 = __hip_bfloat16;
typedef __attribute__((ext_vector_type(8))) short bf16x8;
typedef __attribute__((ext_vector_type(4))) float f32x4;

#define B_ 4
#define T_ 2048
#define H_ 1024
#define DI_ 2048
#define BT_ 8192
#define NC_ 32
#define CHUNK_ 64

__device__ __forceinline__ float bf2f(bf16 x) { return __bfloat162float(x); }
__device__ __forceinline__ bf16 f2bf(float x) { return __float2bfloat16(x); }
__device__ __forceinline__ f32x4 mfma16(bf16x8 a, bf16x8 b, f32x4 c) {
  return __builtin_amdgcn_mfma_f32_16x16x32_bf16(a, b, c, 0, 0, 0);
}
__device__ __forceinline__ void gload_lds16(const bf16* g, bf16* l) {
  __builtin_amdgcn_global_load_lds((const __attribute__((address_space(1))) void*)(g),
                                   (__attribute__((address_space(3))) void*)(l), 16, 0, 0);
}

// ---------------- cast kernels ----------------
__global__ void cast_kernel(const float* __restrict__ in, bf16* __restrict__ out, int n) {
  int i = blockIdx.x * 256 + threadIdx.x;
  int stride = gridDim.x * 256;
  for (; i < n; i += stride) out[i] = f2bf(in[i]);
}

struct bf16q { bf16 a, b, c, d; };
__device__ __forceinline__ void cast4(const float* __restrict__ src, bf16* __restrict__ dst, int q) {
  float4 v = *(const float4*)(src + (size_t)q * 4);
  bf16q t = { f2bf(v.x), f2bf(v.y), f2bf(v.z), f2bf(v.w) };
  *(bf16q*)(dst + (size_t)q * 4) = t;
}

__global__ void fused_cast_kernel(const float* __restrict__ x, const float* __restrict__ w_up,
                                  const float* __restrict__ w_gate, const float* __restrict__ w_q,
                                  const float* __restrict__ w_k, const float* __restrict__ w_g,
                                  const float* __restrict__ w_tau, const float* __restrict__ w_i1,
                                  bf16* __restrict__ x_bf, bf16* __restrict__ wug,
                                  bf16* __restrict__ wqkgt, bf16* __restrict__ wi1p) {
  const int B0 = 0;            // x: 2097152 quads
  const int B1 = 2097152;      // w_up: 524288
  const int B2 = 2621440;      // w_gate: 524288
  const int B3 = 3145728;      // w_q: 32768
  const int B4 = 3178496;      // w_k
  const int B5 = 3211264;      // w_g
  const int B6 = 3244032;      // w_tau
  const int B7 = 3276800;      // wi1p: 65536 (first 8192 from w_i1, rest zero)
  const int END = 3342336;
  int i = blockIdx.x * 256 + threadIdx.x;
  int stride = gridDim.x * 256;
  for (; i < END; i += stride) {
    if (i < B1)      cast4(x,      x_bf,                i - B0);
    else if (i < B2) cast4(w_up,   wug,                 i - B1);
    else if (i < B3) cast4(w_gate, wug + 2097152,       i - B2);
    else if (i < B4) cast4(w_q,    wqkgt,               i - B3);
    else if (i < B5) cast4(w_k,    wqkgt + 131072,      i - B4);
    else if (i < B6) cast4(w_g,    wqkgt + 262144,      i - B5);
    else if (i < B7) cast4(w_tau,  wqkgt + 393216,      i - B6);
    else {
      int q = i - B7;
      if (q < 8192) cast4(w_i1, wi1p, q);
      else { bf16q z = { f2bf(0.f), f2bf(0.f), f2bf(0.f), f2bf(0.f) }; *(bf16q*)(wi1p + (size_t)q * 4) = z; }
    }
  }
}

__global__ void fill_kernel(float* __restrict__ out, float v, int n) {
  int i = blockIdx.x * 256 + threadIdx.x;
  int stride = gridDim.x * 256;
  for (; i < n; i += stride) out[i] = v;
}

// ============ 256x256-tile 8-phase bf16 GEMM (T1+T2+T3+T4+T5) ============
template <int EPI>
__global__ __launch_bounds__(512) void gemm256(
    const bf16* __restrict__ A, const bf16* __restrict__ Bw, int K, int N, int NBN,
    float* __restrict__ Cf, bf16* __restrict__ hid, bf16* __restrict__ shf, bf16* __restrict__ fg) {
  extern __shared__ bf16 lds[];
  bf16* As = lds;
  bf16* Bs = lds + 32768;
  const int tid = threadIdx.x;
  const int lane = tid & 63;
  const int wv = tid >> 6;
  const int wr = wv >> 2;
  const int wc = wv & 3;
  const int cpx = gridDim.x >> 3;
  const int bid = blockIdx.x;
  const int swz = (bid & 7) * cpx + (bid >> 3);
  const int bm = swz / NBN, bn = swz % NBN;
  const size_t arow0 = (size_t)bm * 256;
  const size_t brow0 = (size_t)bn * 256;

  const bf16* gA[2][2]; const bf16* gB[2][2];
  int loff[2][2];
#pragma unroll
  for (int h = 0; h < 2; ++h)
#pragma unroll
    for (int j = 0; j < 2; ++j) {
      int D = h * 16384 + (j * 512 + tid) * 16;
      int L = D ^ (((D >> 9) & 1) << 5);
      int lrow = L >> 7;
      int col = (L & 127) >> 1;
      int arow = ((lrow >> 6) & 1) * 128 + h * 64 + (lrow & 63);
      int lrl = lrow & 127;
      int brow = (lrl >> 5) * 64 + h * 32 + (lrl & 31);
      gA[h][j] = A + (arow0 + arow) * (size_t)K + col;
      gB[h][j] = Bw + (brow0 + brow) * (size_t)K + col;
      loff[h][j] = D >> 1;
    }
#define STAGE_A(buf, h, kt) { gload_lds16(gA[h][0] + (kt), As + (buf) * 16384 + loff[h][0]); \
                              gload_lds16(gA[h][1] + (kt), As + (buf) * 16384 + loff[h][1]); }
#define STAGE_B(buf, h, kt) { gload_lds16(gB[h][0] + (kt), Bs + (buf) * 16384 + loff[h][0]); \
                              gload_lds16(gB[h][1] + (kt), Bs + (buf) * 16384 + loff[h][1]); }

  auto lda = [&](int buf, int mh, int mi, int ks) -> bf16x8 {
    int lrow = (mh * 2 + wr) * 64 + mi * 16 + (lane & 15);
    int byte = lrow * 128 + ks * 64 + (lane >> 4) * 16;
    byte ^= ((byte >> 9) & 1) << 5;
    return *(const bf16x8*)&As[buf * 16384 + (byte >> 1)];
  };
  auto ldb = [&](int buf, int nh, int ni, int ks) -> bf16x8 {
    int lrow = (nh * 4 + wc) * 32 + ni * 16 + (lane & 15);
    int byte = lrow * 128 + ks * 64 + (lane >> 4) * 16;
    byte ^= ((byte >> 9) & 1) << 5;
    return *(const bf16x8*)&Bs[buf * 16384 + (byte >> 1)];
  };

  f32x4 acc[8][4] = {};
  const int NT = K >> 6;
  STAGE_A(0, 0, 0); STAGE_B(0, 0, 0); STAGE_A(0, 1, 0); STAGE_B(0, 1, 0);
  if (NT > 1) { STAGE_A(1, 0, 64); STAGE_B(1, 0, 64); }
  asm volatile("s_waitcnt vmcnt(4)" ::: "memory");
  __syncthreads();

  for (int t = 0; t < NT; ++t) {
    const int cur = t & 1, nxt = cur ^ 1;
    const int kt1 = (t + 1) << 6, kt2 = (t + 2) << 6;
    bf16x8 a0[4][2], a1[4][2], b0[2][2], b1[2][2];
    // ---- phase 1 ----
#pragma unroll
    for (int mi = 0; mi < 4; ++mi) { a0[mi][0] = lda(cur, 0, mi, 0); a0[mi][1] = lda(cur, 0, mi, 1); }
#pragma unroll
    for (int ni = 0; ni < 2; ++ni) { b0[ni][0] = ldb(cur, 0, ni, 0); b0[ni][1] = ldb(cur, 0, ni, 1); }
    if (t + 1 < NT) STAGE_A(nxt, 1, kt1);
    __builtin_amdgcn_s_barrier();
    asm volatile("s_waitcnt lgkmcnt(0)" ::: "memory");
    __builtin_amdgcn_sched_barrier(0);
    __builtin_amdgcn_s_setprio(1);
#pragma unroll
    for (int mi = 0; mi < 4; ++mi)
#pragma unroll
      for (int ni = 0; ni < 2; ++ni) {
        acc[mi][ni] = mfma16(a0[mi][0], b0[ni][0], acc[mi][ni]);
        acc[mi][ni] = mfma16(a0[mi][1], b0[ni][1], acc[mi][ni]);
      }
    __builtin_amdgcn_s_setprio(0);
    __builtin_amdgcn_s_barrier();
    // ---- phase 2 ----
#pragma unroll
    for (int ni = 0; ni < 2; ++ni) { b1[ni][0] = ldb(cur, 1, ni, 0); b1[ni][1] = ldb(cur, 1, ni, 1); }
    if (t + 1 < NT) STAGE_B(nxt, 1, kt1);
    __builtin_amdgcn_s_barrier();
    asm volatile("s_waitcnt lgkmcnt(0)" ::: "memory");
    __builtin_amdgcn_sched_barrier(0);
    __builtin_amdgcn_s_setprio(1);
#pragma unroll
    for (int mi = 0; mi < 4; ++mi)
#pragma unroll
      for (int ni = 0; ni < 2; ++ni) {
        acc[mi][2 + ni] = mfma16(a0[mi][0], b1[ni][0], acc[mi][2 + ni]);
        acc[mi][2 + ni] = mfma16(a0[mi][1], b1[ni][1], acc[mi][2 + ni]);
      }
    __builtin_amdgcn_s_setprio(0);
    __builtin_amdgcn_s_barrier();
    // ---- phase 3 ----
#pragma unroll
    for (int mi = 0; mi < 4; ++mi) { a1[mi][0] = lda(cur, 1, mi, 0); a1[mi][1] = lda(cur, 1, mi, 1); }
    if (t + 2 < NT) STAGE_A(cur, 0, kt2);
    __builtin_amdgcn_s_barrier();
    asm volatile("s_waitcnt lgkmcnt(0)" ::: "memory");
    __builtin_amdgcn_sched_barrier(0);
    __builtin_amdgcn_s_setprio(1);
#pragma unroll
    for (int mi = 0; mi < 4; ++mi)
#pragma unroll
      for (int ni = 0; ni < 2; ++ni) {
        acc[4 + mi][ni] = mfma16(a1[mi][0], b0[ni][0], acc[4 + mi][ni]);
        acc[4 + mi][ni] = mfma16(a1[mi][1], b0[ni][1], acc[4 + mi][ni]);
      }
    __builtin_amdgcn_s_setprio(0);
    __builtin_amdgcn_s_barrier();
    // ---- phase 4 ----
    if (t + 2 < NT) STAGE_B(cur, 0, kt2);
    __builtin_amdgcn_s_barrier();
    __builtin_amdgcn_s_setprio(1);
#pragma unroll
    for (int mi = 0; mi < 4; ++mi)
#pragma unroll
      for (int ni = 0; ni < 2; ++ni) {
        acc[4 + mi][2 + ni] = mfma16(a1[mi][0], b1[ni][0], acc[4 + mi][2 + ni]);
        acc[4 + mi][2 + ni] = mfma16(a1[mi][1], b1[ni][1], acc[4 + mi][2 + ni]);
      }
    __builtin_amdgcn_s_setprio(0);
    if (t < NT - 2) { asm volatile("s_waitcnt vmcnt(4)" ::: "memory"); }
    else            { asm volatile("s_waitcnt vmcnt(0)" ::: "memory"); }
    __builtin_amdgcn_s_barrier();
  }

  const int r0 = wr * 128 + (lane >> 4) * 4;
  const int c0 = wc * 64 + (lane & 15);
#pragma unroll
  for (int mi = 0; mi < 8; ++mi)
#pragma unroll
    for (int ni = 0; ni < 4; ++ni)
#pragma unroll
      for (int r = 0; r < 4; ++r) {
        size_t row = arow0 + r0 + mi * 16 + r;
        int col = (int)brow0 + c0 + ni * 16;
        float v = acc[mi][ni][r];
        if (EPI == 0) {
          Cf[row * (size_t)N + col] = v;
        } else {
          if (col < DI_) {
            hid[row * DI_ + col] = f2bf(v);
            shf[row * DI_ + col] = f2bf(v / (1.f + expf(-v)));
          } else {
            fg[row * DI_ + (col - DI_)] = f2bf(v);
          }
        }
      }
#undef STAGE_A
#undef STAGE_B
}

// ---------------- 2-phase 128x128 GEMM with optional split-K atomic epilogue ----------------
template <int ATOMIC>
__global__ __launch_bounds__(256) void gemm_bt(
    const bf16* __restrict__ A, const bf16* __restrict__ Bw, int K, int N, int kchunk,
    float* __restrict__ Cf) {
  __shared__ bf16 As[128 * 64];
  __shared__ bf16 Bs[128 * 64];
  const int tid = threadIdx.x;
  const int lane = tid & 63;
  const int wave = tid >> 6;
  const int bn = blockIdx.x, bm = blockIdx.y;
  const int wr = (wave >> 1) * 64, wc = (wave & 1) * 64;
  f32x4 acc[4][4] = {};
  const int srow = tid >> 3;
  const int scol = (tid & 7) * 8;
  const size_t arow0 = (size_t)bm * 128;
  const size_t brow0 = (size_t)bn * 128;
  const int k0 = blockIdx.z * kchunk;

  for (int kt = k0; kt < k0 + kchunk; kt += 64) {
#pragma unroll
    for (int i = 0; i < 4; ++i) {
      const bf16* ga = A + (arow0 + i * 32 + srow) * (size_t)K + kt + scol;
      const bf16* gb = Bw + (brow0 + i * 32 + srow) * (size_t)K + kt + scol;
      gload_lds16(ga, &As[(i * 32 + srow) * 64 + scol]);
      gload_lds16(gb, &Bs[(i * 32 + srow) * 64 + scol]);
    }
    asm volatile("s_waitcnt vmcnt(0)" ::: "memory");
    __syncthreads();
#pragma unroll
    for (int ks = 0; ks < 64; ks += 32) {
      bf16x8 af[4], bfr[4];
#pragma unroll
      for (int i = 0; i < 4; ++i) {
        af[i]  = *(const bf16x8*)&As[(wr + i * 16 + (lane & 15)) * 64 + ks + (lane >> 4) * 8];
        bfr[i] = *(const bf16x8*)&Bs[(wc + i * 16 + (lane & 15)) * 64 + ks + (lane >> 4) * 8];
      }
#pragma unroll
      for (int i = 0; i < 4; ++i)
#pragma unroll
        for (int j = 0; j < 4; ++j)
          acc[i][j] = mfma16(af[i], bfr[j], acc[i][j]);
    }
    __syncthreads();
  }

  const int crow = wr + (lane >> 4) * 4;
  const int ccol = wc + (lane & 15);
#pragma unroll
  for (int i = 0; i < 4; ++i)
#pragma unroll
    for (int j = 0; j < 4; ++j)
#pragma unroll
      for (int r = 0; r < 4; ++r) {
        size_t row = arow0 + crow + i * 16 + r;
        int col = (int)brow0 + ccol + j * 16;
        float v = acc[i][j][r];
        if (ATOMIC) atomicAdd(&Cf[row * (size_t)N + col], v);
        else Cf[row * (size_t)N + col] = v;
      }
}

// ---------------- fused gates + chunk-cumsum (CHUNK=64) ----------------
// block = one (b, chunk): 128 blocks x 256 threads
__global__ __launch_bounds__(256) void gates_cum_kernel(const float* __restrict__ proj,
    const float* __restrict__ b_g, const float* __restrict__ b_tau,
    float* __restrict__ qs, float* __restrict__ khat, float* __restrict__ eg,
    bf16* __restrict__ qhat2, float* __restrict__ Dtot) {
  __shared__ float s_gk[64 * 64];   // 16KB
  __shared__ float segsum[4 * 64];
  int tid = threadIdx.x;
  int lane = tid & 63;
  int wvv = tid >> 6;
  int bc = blockIdx.x;
  size_t row0 = (size_t)((bc >> 5) * T_ + (bc & 31) * CHUNK_);
  for (int r = wvv; r < CHUNK_; r += 4) {
    const float* p = proj + (row0 + r) * 256;
    float q  = p[lane];
    float kk = p[64 + lane];
    float zg = p[128 + lane] + b_g[lane];
    float zt = p[192 + lane] + b_tau[lane];
    float gg  = (zg > 20.f) ? zg : log1pf(expf(zg));
    float tau = 1.f / (1.f + expf(-zt));
    float it  = powf(gg, tau);
    float gkv = -gg * tau;
    float s = kk * kk;
#pragma unroll
    for (int off = 32; off > 0; off >>= 1) s += __shfl_xor(s, off);
    float kn = sqrtf(s);
    size_t o = (row0 + r) * 64 + lane;
    qs[o]   = q * 0.125f;
    khat[o] = kk / fmaxf(kn, 1e-12f) * it;
    eg[o]   = expf(gkv);
    s_gk[r * 64 + lane] = gkv;
  }
  __syncthreads();
  float loc = 0.f;
  for (int r = wvv * 16; r < wvv * 16 + 16; ++r) loc += s_gk[r * 64 + lane];
  segsum[wvv * 64 + lane] = loc;
  __syncthreads();
  float gc = 0.f;
  for (int ss = 0; ss < wvv; ++ss) gc += segsum[ss * 64 + lane];
  for (int r = wvv * 16; r < wvv * 16 + 16; ++r) {
    gc += s_gk[r * 64 + lane];
    float qv = proj[(row0 + r) * 256 + lane] * 0.125f;
    qhat2[(row0 + r) * 64 + lane] = f2bf(qv * expf(gc));
  }
  if (wvv == 3) Dtot[bc * 64 + lane] = expf(gc);
}

// ---------------- v = sigmoid(i1 @ w_i2^T + b_i2) * hid ----------------
__global__ __launch_bounds__(256) void vgate_kernel(const bf16* __restrict__ hid,
    const float* __restrict__ i1, const float* __restrict__ w_i2,
    const float* __restrict__ b_i2, bf16* __restrict__ v) {
  __shared__ float s_w2[16 * 256];
  int tid = threadIdx.x;
  int di0 = blockIdx.x * 256;
  int r0 = blockIdx.y * 128;
#pragma unroll
  for (int l = 0; l < 16; ++l)
    s_w2[l * 256 + tid] = w_i2[(size_t)(di0 + tid) * 16 + l];
  __syncthreads();
  float bi = b_i2[di0 + tid];
  for (int rr = 0; rr < 128; ++rr) {
    size_t r = r0 + rr;
    const float* ip = &i1[r * 128];
    float z = bi;
#pragma unroll
    for (int l = 0; l < 16; ++l) z += ip[l] * s_w2[l * 256 + tid];
    float hv = bf2f(hid[r * DI_ + di0 + tid]);
    float ig = 1.f / (1.f + expf(-z));
    v[r * DI_ + di0 + tid] = f2bf(ig * hv);
  }
}

// ---------------- chunk-local scan (CHUNK=64); in-place v -> o; hloc di-major ----------------
__global__ __launch_bounds__(256) void scan_kernel(const float* __restrict__ eg,
    const float* __restrict__ khat, const float* __restrict__ qs,
    bf16* vo, bf16* __restrict__ hloc) {
  __shared__ float s[3 * 8 * 64];
  int tid = threadIdx.x;
  int b = blockIdx.z, c = blockIdx.y;
  int di = blockIdx.x * 256 + tid;
  float h[64];
#pragma unroll
  for (int k = 0; k < 64; ++k) h[k] = 0.f;
  int row0 = b * T_ + c * CHUNK_;
  for (int t0 = 0; t0 < CHUNK_; t0 += 8) {
    size_t base = (size_t)(row0 + t0) * 64;
    __syncthreads();
    for (int i = tid; i < 512; i += 256) {
      s[i] = eg[base + i];
      s[512 + i] = khat[base + i];
      s[1024 + i] = qs[base + i];
    }
    __syncthreads();
    for (int tt = 0; tt < 8; ++tt) {
      size_t row = row0 + t0 + tt;
      float vv = bf2f(vo[row * DI_ + di]);
      const float* se = &s[tt * 64];
      const float* sk = &s[512 + tt * 64];
      const float* sq = &s[1024 + tt * 64];
      float oa = 0.f;
#pragma unroll
      for (int k = 0; k < 64; k += 4) {
        float4 e4 = *(const float4*)&se[k];
        float4 k4 = *(const float4*)&sk[k];
        float4 q4 = *(const float4*)&sq[k];
        h[k]     = h[k]     * e4.x + k4.x * vv; oa += q4.x * h[k];
        h[k + 1] = h[k + 1] * e4.y + k4.y * vv; oa += q4.y * h[k + 1];
        h[k + 2] = h[k + 2] * e4.z + k4.z * vv; oa += q4.z * h[k + 2];
        h[k + 3] = h[k + 3] * e4.w + k4.w * vv; oa += q4.w * h[k + 3];
      }
      vo[row * DI_ + di] = f2bf(oa);   // in-place: v[row,di] dead after read above
    }
  }
  // hloc layout: [(b*NC+c)*DI + di][k]  (k contiguous per thread)
  size_t hb = ((size_t)((b * NC_ + c)) * DI_ + di) * 64;
#pragma unroll
  for (int k = 0; k < 64; k += 4) {
    ushort4 t;
    t.x = __bfloat16_as_ushort(f2bf(h[k]));
    t.y = __bfloat16_as_ushort(f2bf(h[k + 1]));
    t.z = __bfloat16_as_ushort(f2bf(h[k + 2]));
    t.w = __bfloat16_as_ushort(f2bf(h[k + 3]));
    *(ushort4*)(hloc + hb + k) = t;
  }
}

// ---------------- cross-chunk state combine (hloc di-major, in-place -> h_in) ----------------
__global__ void combine_kernel(bf16* __restrict__ h, const float* __restrict__ Dtot) {
  int tid = threadIdx.x;
  int k = tid & 63;
  int di = blockIdx.x * 4 + (tid >> 6);
  int b = blockIdx.y;
  float run = 0.f;
#pragma unroll
  for (int c = 0; c < NC_; ++c) {
    size_t idx = ((size_t)((b * NC_ + c)) * DI_ + di) * 64 + k;
    float t = bf2f(h[idx]);
    h[idx] = f2bf(run);
    run = run * Dtot[(b * NC_ + c) * 64 + k] + t;
  }
}

// ---------------- inter-chunk correction via MFMA: o += qhat2 @ h_in ----------------
// pure-register kernel: A,B fragments straight from global; 1024 blocks x 4 waves
__global__ __launch_bounds__(256) void inter_mfma(const bf16* __restrict__ hloc,
    const bf16* __restrict__ qhat2, bf16* o) {
  int tid = threadIdx.x;
  int lane = tid & 63;
  int w = tid >> 6;
  int di0 = blockIdx.x * 256;
  int c = blockIdx.y, b = blockIdx.z;
  int row0 = b * T_ + c * CHUNK_;
  size_t hb = (size_t)(b * NC_ + c) * DI_ * 64;
  int diw = di0 + w * 64;
  f32x4 acc[4][4] = {};
  bf16x8 af[4][2], bw[4][2];
#pragma unroll
  for (int mi = 0; mi < 4; ++mi)
#pragma unroll
    for (int ks = 0; ks < 2; ++ks)
      af[mi][ks] = *(const bf16x8*)(qhat2 + (size_t)(row0 + mi * 16 + (lane & 15)) * 64 + ks * 32 + (lane >> 4) * 8);
#pragma unroll
  for (int ni = 0; ni < 4; ++ni)
#pragma unroll
    for (int ks = 0; ks < 2; ++ks)
      bw[ni][ks] = *(const bf16x8*)(hloc + hb + (size_t)(diw + ni * 16 + (lane & 15)) * 64 + ks * 32 + (lane >> 4) * 8);
#pragma unroll
  for (int mi = 0; mi < 4; ++mi)
#pragma unroll
    for (int ni = 0; ni < 4; ++ni) {
      acc[mi][ni] = mfma16(af[mi][0], bw[ni][0], acc[mi][ni]);
      acc[mi][ni] = mfma16(af[mi][1], bw[ni][1], acc[mi][ni]);
    }
#pragma unroll
  for (int mi = 0; mi < 4; ++mi)
#pragma unroll
    for (int ni = 0; ni < 4; ++ni)
#pragma unroll
      for (int r = 0; r < 4; ++r) {
        size_t row = row0 + mi * 16 + (lane >> 4) * 4 + r;
        int dic = diw + ni * 16 + (lane & 15);
        size_t oi = row * DI_ + dic;
        o[oi] = f2bf(bf2f(o[oi]) + acc[mi][ni][r]);
      }
}

// ---------------- residual + gated RMSNorm (in-place on o) ----------------
__global__ __launch_bounds__(256) void norm_kernel(bf16* o_io,
    const bf16* __restrict__ shf, const bf16* __restrict__ fg,
    const float* __restrict__ res_w, const float* __restrict__ norm_w) {
  __shared__ float sred[4];
  int tid = threadIdx.x;
  size_t row = blockIdx.x;
  float vals[8];
  float ss = 0.f;
#pragma unroll
  for (int j = 0; j < 8; ++j) {
    int di = tid + j * 256;
    float x2 = bf2f(o_io[row * DI_ + di]) + bf2f(shf[row * DI_ + di]) * res_w[di];
    vals[j] = x2;
    ss += x2 * x2;
  }
#pragma unroll
  for (int off = 32; off > 0; off >>= 1) ss += __shfl_xor(ss, off);
  if ((tid & 63) == 0) sred[tid >> 6] = ss;
  __syncthreads();
  float tot = sred[0] + sred[1] + sred[2] + sred[3];
  float rinv = rsqrtf(tot / DI_ + 1e-5f);
#pragma unroll
  for (int j = 0; j < 8; ++j) {
    int di = tid + j * 256;
    float fgs = 1.f / (1.f + expf(-bf2f(fg[row * DI_ + di])));
    o_io[row * DI_ + di] = f2bf(vals[j] * rinv * norm_w[di] * fgs);
  }
}

// ---------------- host launcher ----------------
// Workspace (TOTAL 180,912,128 B < proven 200,818,688):
//  front [0, 72,876,032): x_bf, wug, wqkgt, wi1p, proj, i1, hid — dead after vgate
//    overlays: hloc @0 (33,554,432, from scan), wdown @35,127,296 (4,194,304, after vgate)
//  72,876,032: vb/o/o3 (in-place chain v->o->o3)  33,554,432
//  106,430,464: shf 33,554,432
//  139,984,896: fgb 33,554,432
//  173,539,328: qs 2MB | 175,636,480: khat 2MB | 177,733,632: eg 2MB
//  179,830,784: qhat2(bf16) 1MB | 180,879,360: Dtot 32KB
extern "C" void kernel_launch(void* const* d_in, const int* in_sizes, int n_in,
                              void* d_out, int out_size, void* d_ws, size_t ws_size,
                              hipStream_t stream) {
  const float* x      = (const float*)d_in[0];
  const float* w_gate = (const float*)d_in[1];
  const float* w_up   = (const float*)d_in[2];
  const float* w_down = (const float*)d_in[3];
  const float* w_q    = (const float*)d_in[4];
  const float* w_k    = (const float*)d_in[5];
  const float* w_g    = (const float*)d_in[6];
  const float* b_g    = (const float*)d_in[7];
  const float* w_tau  = (const float*)d_in[8];
  const float* b_tau  = (const float*)d_in[9];
  const float* w_i1   = (const float*)d_in[10];
  const float* w_i2   = (const float*)d_in[11];
  const float* b_i2   = (const float*)d_in[12];
  const float* norm_w = (const float*)d_in[13];
  const float* res_w  = (const float*)d_in[14];
  float* out = (float*)d_out;

  char* base = (char*)d_ws;
  bf16*  x_bf  = (bf16*)(base + 0);
  bf16*  wug   = (bf16*)(base + 16777216);
  bf16*  wqkgt = (bf16*)(base + 25165824);
  bf16*  wi1p  = (bf16*)(base + 26214400);
  float* proj  = (float*)(base + 26738688);
  float* i1    = (float*)(base + 35127296);
  bf16*  hid   = (bf16*)(base + 39321600);
  bf16*  hloc  = (bf16*)(base + 0);            // overlay (from scan)
  bf16*  wdown = (bf16*)(base + 35127296);     // overlay (after vgate)
  bf16*  vo    = (bf16*)(base + 72876032);     // v -> o -> o3 in-place
  bf16*  shf   = (bf16*)(base + 106430464);
  bf16*  fgb   = (bf16*)(base + 139984896);
  float* qs    = (float*)(base + 173539328);
  float* khat  = (float*)(base + 175636480);
  float* eg    = (float*)(base + 177733632);
  bf16*  qhat2 = (bf16*)(base + 179830784);
  float* Dtot  = (float*)(base + 180879360);
  const size_t TOTAL = 180912128;
  if (ws_size < TOTAL) {
    fill_kernel<<<dim3(512), 256, 0, stream>>>(out, 1.0e6f, out_size);
    return;
  }

  hipFuncSetAttribute((const void*)gemm256<1>, hipFuncAttributeMaxDynamicSharedMemorySize, 131072);
  hipFuncSetAttribute((const void*)gemm256<0>, hipFuncAttributeMaxDynamicSharedMemorySize, 131072);

  hipMemsetAsync(proj, 0, (size_t)BT_ * 256 * 4, stream);
  hipMemsetAsync(i1, 0, (size_t)BT_ * 128 * 4, stream);

  fused_cast_kernel<<<dim3(2048), 256, 0, stream>>>(x, w_up, w_gate, w_q, w_k, w_g, w_tau, w_i1,
                                                    x_bf, wug, wqkgt, wi1p);

  // GEMM1: [hid|fg] = x @ [w_up;w_gate]^T + SiLU
  gemm256<1><<<dim3(512), 512, 131072, stream>>>(x_bf, wug, H_, 4096, 16, nullptr, hid, shf, fgb);
  // GEMM2: proj = shf @ [wq;wk;wg;wtau]^T  (split-K x4, atomic)
  gemm_bt<1><<<dim3(2, 64, 4), 256, 0, stream>>>(shf, wqkgt, DI_, 256, 512, proj);
  // GEMM3: i1 = hid @ w_i1p^T  (split-K x8, atomic)
  gemm_bt<1><<<dim3(1, 64, 8), 256, 0, stream>>>(hid, wi1p, DI_, 128, 256, i1);

  gates_cum_kernel<<<dim3(128), 256, 0, stream>>>(proj, b_g, b_tau, qs, khat, eg, qhat2, Dtot);
  vgate_kernel<<<dim3(8, 64), 256, 0, stream>>>(hid, i1, w_i2, b_i2, vo);
  // front dead -> overlays valid; start wdown cast early (independent)
  cast_kernel<<<dim3(512), 256, 0, stream>>>(w_down, wdown, H_ * DI_);

  scan_kernel<<<dim3(8, NC_, B_), 256, 0, stream>>>(eg, khat, qs, vo, hloc);
  combine_kernel<<<dim3(512, B_), 256, 0, stream>>>(hloc, Dtot);
  inter_mfma<<<dim3(8, NC_, B_), 256, 0, stream>>>(hloc, qhat2, vo);

  norm_kernel<<<dim3(BT_), 256, 0, stream>>>(vo, shf, fgb, res_w, norm_w);
  // GEMM4: out = o3 @ w_down^T
  gemm256<0><<<dim3(128), 512, 131072, stream>>>(vo, wdown, DI_, H_, 4, out, nullptr, nullptr, nullptr);
}

// Round 5
// 562.616 us; speedup vs baseline: 1.2269x; 1.0677x over previous
//
#include <hip/hip_runtime.h>
#include <hip/hip_bf16.h>
#include <math.h>

using bf16 = __hip_bfloat16;
typedef __attribute__((ext_vector_type(8))) short bf16x8;
typedef __attribute__((ext_vector_type(4))) float f32x4;

#define B_ 4
#define T_ 2048
#define H_ 1024
#define DI_ 2048
#define BT_ 8192
#define NC_ 32
#define CHUNK_ 64

__device__ __forceinline__ float bf2f(bf16 x) { return __bfloat162float(x); }
__device__ __forceinline__ bf16 f2bf(float x) { return __float2bfloat16(x); }
__device__ __forceinline__ f32x4 mfma16(bf16x8 a, bf16x8 b, f32x4 c) {
  return __builtin_amdgcn_mfma_f32_16x16x32_bf16(a, b, c, 0, 0, 0);
}
__device__ __forceinline__ void gload_lds16(const bf16* g, bf16* l) {
  __builtin_amdgcn_global_load_lds((const __attribute__((address_space(1))) void*)(g),
                                   (__attribute__((address_space(3))) void*)(l), 16, 0, 0);
}

// ---------------- cast kernels ----------------
__global__ void cast_kernel(const float* __restrict__ in, bf16* __restrict__ out, int n) {
  int i = blockIdx.x * 256 + threadIdx.x;
  int stride = gridDim.x * 256;
  for (; i < n; i += stride) out[i] = f2bf(in[i]);
}

struct bf16q { bf16 a, b, c, d; };
__device__ __forceinline__ void cast4(const float* __restrict__ src, bf16* __restrict__ dst, int q) {
  float4 v = *(const float4*)(src + (size_t)q * 4);
  bf16q t = { f2bf(v.x), f2bf(v.y), f2bf(v.z), f2bf(v.w) };
  *(bf16q*)(dst + (size_t)q * 4) = t;
}

__global__ void fused_cast_kernel(const float* __restrict__ x, const float* __restrict__ w_up,
                                  const float* __restrict__ w_gate, const float* __restrict__ w_q,
                                  const float* __restrict__ w_k, const float* __restrict__ w_g,
                                  const float* __restrict__ w_tau, const float* __restrict__ w_i1,
                                  bf16* __restrict__ x_bf, bf16* __restrict__ wug,
                                  bf16* __restrict__ wqkgt, bf16* __restrict__ wi1p) {
  const int B1 = 2097152;      // x quads
  const int B2 = 2621440;      // + w_up
  const int B3 = 3145728;      // + w_gate
  const int B4 = 3178496;      // + w_q
  const int B5 = 3211264;      // + w_k
  const int B6 = 3244032;      // + w_g
  const int B7 = 3276800;      // + w_tau
  const int END = 3342336;     // + wi1p (pad)
  int i = blockIdx.x * 256 + threadIdx.x;
  int stride = gridDim.x * 256;
  for (; i < END; i += stride) {
    if (i < B1)      cast4(x,      x_bf,                i);
    else if (i < B2) cast4(w_up,   wug,                 i - B1);
    else if (i < B3) cast4(w_gate, wug + 2097152,       i - B2);
    else if (i < B4) cast4(w_q,    wqkgt,               i - B3);
    else if (i < B5) cast4(w_k,    wqkgt + 131072,      i - B4);
    else if (i < B6) cast4(w_g,    wqkgt + 262144,      i - B5);
    else if (i < B7) cast4(w_tau,  wqkgt + 393216,      i - B6);
    else {
      int q = i - B7;
      if (q < 8192) cast4(w_i1, wi1p, q);
      else { bf16q z = { f2bf(0.f), f2bf(0.f), f2bf(0.f), f2bf(0.f) }; *(bf16q*)(wi1p + (size_t)q * 4) = z; }
    }
  }
}

__global__ void fill_kernel(float* __restrict__ out, float v, int n) {
  int i = blockIdx.x * 256 + threadIdx.x;
  int stride = gridDim.x * 256;
  for (; i < n; i += stride) out[i] = v;
}

// ============ 256x256-tile 8-phase bf16 GEMM (T1+T2+T3+T4+T5) ============
// EPI 0: fp32 store. EPI 1: hid/shf/fg epilogue. EPI 2: atomic fp32 (split-K via blockIdx.y).
template <int EPI>
__global__ __launch_bounds__(512) void gemm256(
    const bf16* __restrict__ A, const bf16* __restrict__ Bw, int K, int kstride, int N, int NBN,
    float* __restrict__ Cf, bf16* __restrict__ hid, bf16* __restrict__ shf, bf16* __restrict__ fg) {
  extern __shared__ bf16 lds[];
  bf16* As = lds;
  bf16* Bs = lds + 32768;
  const int tid = threadIdx.x;
  const int lane = tid & 63;
  const int wv = tid >> 6;
  const int wr = wv >> 2;
  const int wc = wv & 3;
  const int cpx = gridDim.x >> 3;
  const int bid = blockIdx.x;
  const int swz = (bid & 7) * cpx + (bid >> 3);
  const int bm = swz / NBN, bn = swz % NBN;
  const size_t arow0 = (size_t)bm * 256;
  const size_t brow0 = (size_t)bn * 256;
  const int koff = blockIdx.y * K;

  const bf16* gA[2][2]; const bf16* gB[2][2];
  int loff[2][2];
#pragma unroll
  for (int h = 0; h < 2; ++h)
#pragma unroll
    for (int j = 0; j < 2; ++j) {
      int D = h * 16384 + (j * 512 + tid) * 16;
      int L = D ^ (((D >> 9) & 1) << 5);
      int lrow = L >> 7;
      int col = (L & 127) >> 1;
      int arow = ((lrow >> 6) & 1) * 128 + h * 64 + (lrow & 63);
      int lrl = lrow & 127;
      int brow = (lrl >> 5) * 64 + h * 32 + (lrl & 31);
      gA[h][j] = A + (arow0 + arow) * (size_t)kstride + koff + col;
      gB[h][j] = Bw + (brow0 + brow) * (size_t)kstride + koff + col;
      loff[h][j] = D >> 1;
    }
#define STAGE_A(buf, h, kt) { gload_lds16(gA[h][0] + (kt), As + (buf) * 16384 + loff[h][0]); \
                              gload_lds16(gA[h][1] + (kt), As + (buf) * 16384 + loff[h][1]); }
#define STAGE_B(buf, h, kt) { gload_lds16(gB[h][0] + (kt), Bs + (buf) * 16384 + loff[h][0]); \
                              gload_lds16(gB[h][1] + (kt), Bs + (buf) * 16384 + loff[h][1]); }

  auto lda = [&](int buf, int mh, int mi, int ks) -> bf16x8 {
    int lrow = (mh * 2 + wr) * 64 + mi * 16 + (lane & 15);
    int byte = lrow * 128 + ks * 64 + (lane >> 4) * 16;
    byte ^= ((byte >> 9) & 1) << 5;
    return *(const bf16x8*)&As[buf * 16384 + (byte >> 1)];
  };
  auto ldb = [&](int buf, int nh, int ni, int ks) -> bf16x8 {
    int lrow = (nh * 4 + wc) * 32 + ni * 16 + (lane & 15);
    int byte = lrow * 128 + ks * 64 + (lane >> 4) * 16;
    byte ^= ((byte >> 9) & 1) << 5;
    return *(const bf16x8*)&Bs[buf * 16384 + (byte >> 1)];
  };

  f32x4 acc[8][4] = {};
  const int NT = K >> 6;
  STAGE_A(0, 0, 0); STAGE_B(0, 0, 0); STAGE_A(0, 1, 0); STAGE_B(0, 1, 0);
  if (NT > 1) { STAGE_A(1, 0, 64); STAGE_B(1, 0, 64); }
  asm volatile("s_waitcnt vmcnt(4)" ::: "memory");
  __syncthreads();

  for (int t = 0; t < NT; ++t) {
    const int cur = t & 1, nxt = cur ^ 1;
    const int kt1 = (t + 1) << 6, kt2 = (t + 2) << 6;
    bf16x8 a0[4][2], a1[4][2], b0[2][2], b1[2][2];
    // ---- phase 1 ----
#pragma unroll
    for (int mi = 0; mi < 4; ++mi) { a0[mi][0] = lda(cur, 0, mi, 0); a0[mi][1] = lda(cur, 0, mi, 1); }
#pragma unroll
    for (int ni = 0; ni < 2; ++ni) { b0[ni][0] = ldb(cur, 0, ni, 0); b0[ni][1] = ldb(cur, 0, ni, 1); }
    if (t + 1 < NT) STAGE_A(nxt, 1, kt1);
    __builtin_amdgcn_s_barrier();
    asm volatile("s_waitcnt lgkmcnt(0)" ::: "memory");
    __builtin_amdgcn_sched_barrier(0);
    __builtin_amdgcn_s_setprio(1);
#pragma unroll
    for (int mi = 0; mi < 4; ++mi)
#pragma unroll
      for (int ni = 0; ni < 2; ++ni) {
        acc[mi][ni] = mfma16(a0[mi][0], b0[ni][0], acc[mi][ni]);
        acc[mi][ni] = mfma16(a0[mi][1], b0[ni][1], acc[mi][ni]);
      }
    __builtin_amdgcn_s_setprio(0);
    __builtin_amdgcn_s_barrier();
    // ---- phase 2 ----
#pragma unroll
    for (int ni = 0; ni < 2; ++ni) { b1[ni][0] = ldb(cur, 1, ni, 0); b1[ni][1] = ldb(cur, 1, ni, 1); }
    if (t + 1 < NT) STAGE_B(nxt, 1, kt1);
    __builtin_amdgcn_s_barrier();
    asm volatile("s_waitcnt lgkmcnt(0)" ::: "memory");
    __builtin_amdgcn_sched_barrier(0);
    __builtin_amdgcn_s_setprio(1);
#pragma unroll
    for (int mi = 0; mi < 4; ++mi)
#pragma unroll
      for (int ni = 0; ni < 2; ++ni) {
        acc[mi][2 + ni] = mfma16(a0[mi][0], b1[ni][0], acc[mi][2 + ni]);
        acc[mi][2 + ni] = mfma16(a0[mi][1], b1[ni][1], acc[mi][2 + ni]);
      }
    __builtin_amdgcn_s_setprio(0);
    __builtin_amdgcn_s_barrier();
    // ---- phase 3 ----
#pragma unroll
    for (int mi = 0; mi < 4; ++mi) { a1[mi][0] = lda(cur, 1, mi, 0); a1[mi][1] = lda(cur, 1, mi, 1); }
    if (t + 2 < NT) STAGE_A(cur, 0, kt2);
    __builtin_amdgcn_s_barrier();
    asm volatile("s_waitcnt lgkmcnt(0)" ::: "memory");
    __builtin_amdgcn_sched_barrier(0);
    __builtin_amdgcn_s_setprio(1);
#pragma unroll
    for (int mi = 0; mi < 4; ++mi)
#pragma unroll
      for (int ni = 0; ni < 2; ++ni) {
        acc[4 + mi][ni] = mfma16(a1[mi][0], b0[ni][0], acc[4 + mi][ni]);
        acc[4 + mi][ni] = mfma16(a1[mi][1], b0[ni][1], acc[4 + mi][ni]);
      }
    __builtin_amdgcn_s_setprio(0);
    __builtin_amdgcn_s_barrier();
    // ---- phase 4 ----
    if (t + 2 < NT) STAGE_B(cur, 0, kt2);
    __builtin_amdgcn_s_barrier();
    __builtin_amdgcn_s_setprio(1);
#pragma unroll
    for (int mi = 0; mi < 4; ++mi)
#pragma unroll
      for (int ni = 0; ni < 2; ++ni) {
        acc[4 + mi][2 + ni] = mfma16(a1[mi][0], b1[ni][0], acc[4 + mi][2 + ni]);
        acc[4 + mi][2 + ni] = mfma16(a1[mi][1], b1[ni][1], acc[4 + mi][2 + ni]);
      }
    __builtin_amdgcn_s_setprio(0);
    if (t < NT - 2) { asm volatile("s_waitcnt vmcnt(4)" ::: "memory"); }
    else            { asm volatile("s_waitcnt vmcnt(0)" ::: "memory"); }
    __builtin_amdgcn_s_barrier();
  }

  const int r0 = wr * 128 + (lane >> 4) * 4;
  const int c0 = wc * 64 + (lane & 15);
#pragma unroll
  for (int mi = 0; mi < 8; ++mi)
#pragma unroll
    for (int ni = 0; ni < 4; ++ni)
#pragma unroll
      for (int r = 0; r < 4; ++r) {
        size_t row = arow0 + r0 + mi * 16 + r;
        int col = (int)brow0 + c0 + ni * 16;
        float v = acc[mi][ni][r];
        if (EPI == 0) {
          Cf[row * (size_t)N + col] = v;
        } else if (EPI == 2) {
          atomicAdd(&Cf[row * (size_t)N + col], v);
        } else {
          if (col < DI_) {
            hid[row * DI_ + col] = f2bf(v);
            shf[row * DI_ + col] = f2bf(v / (1.f + expf(-v)));
          } else {
            fg[row * DI_ + (col - DI_)] = f2bf(v);
          }
        }
      }
#undef STAGE_A
#undef STAGE_B
}

// ---------------- 2-phase 128x128 GEMM with split-K atomic epilogue ----------------
template <int ATOMIC>
__global__ __launch_bounds__(256) void gemm_bt(
    const bf16* __restrict__ A, const bf16* __restrict__ Bw, int K, int N, int kchunk,
    float* __restrict__ Cf) {
  __shared__ bf16 As[128 * 64];
  __shared__ bf16 Bs[128 * 64];
  const int tid = threadIdx.x;
  const int lane = tid & 63;
  const int wave = tid >> 6;
  const int bn = blockIdx.x, bm = blockIdx.y;
  const int wr = (wave >> 1) * 64, wc = (wave & 1) * 64;
  f32x4 acc[4][4] = {};
  const int srow = tid >> 3;
  const int scol = (tid & 7) * 8;
  const size_t arow0 = (size_t)bm * 128;
  const size_t brow0 = (size_t)bn * 128;
  const int k0 = blockIdx.z * kchunk;

  for (int kt = k0; kt < k0 + kchunk; kt += 64) {
#pragma unroll
    for (int i = 0; i < 4; ++i) {
      const bf16* ga = A + (arow0 + i * 32 + srow) * (size_t)K + kt + scol;
      const bf16* gb = Bw + (brow0 + i * 32 + srow) * (size_t)K + kt + scol;
      gload_lds16(ga, &As[(i * 32 + srow) * 64 + scol]);
      gload_lds16(gb, &Bs[(i * 32 + srow) * 64 + scol]);
    }
    asm volatile("s_waitcnt vmcnt(0)" ::: "memory");
    __syncthreads();
#pragma unroll
    for (int ks = 0; ks < 64; ks += 32) {
      bf16x8 af[4], bfr[4];
#pragma unroll
      for (int i = 0; i < 4; ++i) {
        af[i]  = *(const bf16x8*)&As[(wr + i * 16 + (lane & 15)) * 64 + ks + (lane >> 4) * 8];
        bfr[i] = *(const bf16x8*)&Bs[(wc + i * 16 + (lane & 15)) * 64 + ks + (lane >> 4) * 8];
      }
#pragma unroll
      for (int i = 0; i < 4; ++i)
#pragma unroll
        for (int j = 0; j < 4; ++j)
          acc[i][j] = mfma16(af[i], bfr[j], acc[i][j]);
    }
    __syncthreads();
  }

  const int crow = wr + (lane >> 4) * 4;
  const int ccol = wc + (lane & 15);
#pragma unroll
  for (int i = 0; i < 4; ++i)
#pragma unroll
    for (int j = 0; j < 4; ++j)
#pragma unroll
      for (int r = 0; r < 4; ++r) {
        size_t row = arow0 + crow + i * 16 + r;
        int col = (int)brow0 + ccol + j * 16;
        float v = acc[i][j][r];
        if (ATOMIC) atomicAdd(&Cf[row * (size_t)N + col], v);
        else Cf[row * (size_t)N + col] = v;
      }
}

// ---------------- fused gates + chunk-cumsum -> bounded bf16 decay factors ----------------
// outputs: qhat2[t,k]=q*scale*e^{gc_t}, kt0[s,k]=khat*e^{-gc_s}, ktEt[k,s]=khat*e^{gc_end-gc_s},
//          Dtot[k]=e^{gc_end}.  gc = within-chunk cumsum (<=0).
__global__ __launch_bounds__(256) void gates_cum_kernel(const float* __restrict__ proj,
    const float* __restrict__ b_g, const float* __restrict__ b_tau,
    bf16* __restrict__ qhat2, bf16* __restrict__ kt0, bf16* __restrict__ ktEt,
    float* __restrict__ Dtot) {
  __shared__ float s_gk[64 * 64];   // gkv, then gc
  __shared__ float s_kh[64 * 64];   // khat
  __shared__ float segsum[4 * 64];
  int tid = threadIdx.x;
  int lane = tid & 63;
  int wvv = tid >> 6;
  int bc = blockIdx.x;
  size_t row0 = (size_t)((bc >> 5) * T_ + (bc & 31) * CHUNK_);
  for (int r = wvv; r < CHUNK_; r += 4) {
    const float* p = proj + (row0 + r) * 256;
    float kk = p[64 + lane];
    float zg = p[128 + lane] + b_g[lane];
    float zt = p[192 + lane] + b_tau[lane];
    float gg  = (zg > 20.f) ? zg : log1pf(expf(zg));
    float tau = 1.f / (1.f + expf(-zt));
    float it  = powf(gg, tau);
    float gkv = -gg * tau;
    float s = kk * kk;
#pragma unroll
    for (int off = 32; off > 0; off >>= 1) s += __shfl_xor(s, off);
    float kn = sqrtf(s);
    s_kh[r * 64 + lane] = kk / fmaxf(kn, 1e-12f) * it;
    s_gk[r * 64 + lane] = gkv;
  }
  __syncthreads();
  float loc = 0.f;
  for (int r = wvv * 16; r < wvv * 16 + 16; ++r) loc += s_gk[r * 64 + lane];
  segsum[wvv * 64 + lane] = loc;
  __syncthreads();
  float gc = 0.f;
  for (int ss = 0; ss < wvv; ++ss) gc += segsum[ss * 64 + lane];
  for (int r = wvv * 16; r < wvv * 16 + 16; ++r) {
    gc += s_gk[r * 64 + lane];
    float qv = proj[(row0 + r) * 256 + lane] * 0.125f;
    qhat2[(row0 + r) * 64 + lane] = f2bf(qv * expf(gc));
    s_gk[r * 64 + lane] = gc;       // overwrite gkv -> gc (same thread, same slot)
  }
  __syncthreads();
  float gcend = s_gk[63 * 64 + lane];
  for (int r = wvv; r < CHUNK_; r += 4) {
    float gcr = s_gk[r * 64 + lane];
    float kh  = s_kh[r * 64 + lane];
    kt0[(row0 + r) * 64 + lane] = f2bf(kh * expf(-gcr));
    ktEt[((size_t)bc * 64 + lane) * 64 + r] = f2bf(kh * expf(gcend - gcr));
  }
  if (tid < 64) Dtot[bc * 64 + tid] = expf(s_gk[63 * 64 + tid]);
}

// ---------------- v-gate fused with transpose: Vt[b][di][t] = sigmoid(i1@w2+b)*hid ----------------
// grid (T/64, DI/64, B), 256 thr
__global__ __launch_bounds__(256) void vgate_t_kernel(const bf16* __restrict__ hid,
    const float* __restrict__ i1, const float* __restrict__ w_i2, const float* __restrict__ b_i2,
    bf16* __restrict__ Vt) {
  __shared__ float s_w2[16 * 64];
  __shared__ bf16 tile[64][65];
  int tid = threadIdx.x;
  int tt = blockIdx.x, dt = blockIdx.y, b = blockIdx.z;
  int di0 = dt * 64;
  size_t row0 = (size_t)b * T_ + tt * 64;
  {
    int d = tid & 63, l4 = tid >> 6;
#pragma unroll
    for (int l = l4 * 4; l < l4 * 4 + 4; ++l)
      s_w2[l * 64 + d] = w_i2[(size_t)(di0 + d) * 16 + l];
  }
  __syncthreads();
  {
    int d = tid & 63, rb = tid >> 6;
    float bi = b_i2[di0 + d];
    for (int j = 0; j < 16; ++j) {
      int r = rb + 4 * j;
      const float* ip = &i1[(row0 + r) * 128];
      float z = bi;
#pragma unroll
      for (int l = 0; l < 16; ++l) z += ip[l] * s_w2[l * 64 + d];
      float hv = bf2f(hid[(row0 + r) * DI_ + di0 + d]);
      tile[d][r] = f2bf(hv / (1.f + expf(-z)));
    }
  }
  __syncthreads();
  {
    int t = tid & 63, db = tid >> 6;
    for (int j = 0; j < 16; ++j) {
      int d = db + 4 * j;
      Vt[((size_t)b * DI_ + di0 + d) * T_ + tt * 64 + t] = tile[d][t];
    }
  }
}

// ---------------- intra-chunk score matrix: A = tril(qhat2 @ kt0^T), bf16 ----------------
// grid B*NC = 128, 256 thr (wave w -> t rows 16w..16w+15)
__global__ __launch_bounds__(256) void intraA_kernel(const bf16* __restrict__ qhat2,
    const bf16* __restrict__ kt0, bf16* __restrict__ Ag) {
  int tid = threadIdx.x, lane = tid & 63, w = tid >> 6;
  int bc = blockIdx.x;
  size_t row0 = (size_t)((bc >> 5) * T_ + (bc & 31) * CHUNK_);
  f32x4 acc[4] = {};
  bf16x8 a[2], y[4][2];
#pragma unroll
  for (int ks = 0; ks < 2; ++ks)
    a[ks] = *(const bf16x8*)(qhat2 + (row0 + w * 16 + (lane & 15)) * 64 + ks * 32 + (lane >> 4) * 8);
#pragma unroll
  for (int ni = 0; ni < 4; ++ni)
#pragma unroll
    for (int ks = 0; ks < 2; ++ks)
      y[ni][ks] = *(const bf16x8*)(kt0 + (row0 + ni * 16 + (lane & 15)) * 64 + ks * 32 + (lane >> 4) * 8);
#pragma unroll
  for (int ni = 0; ni < 4; ++ni) {
    acc[ni] = mfma16(a[0], y[ni][0], acc[ni]);
    acc[ni] = mfma16(a[1], y[ni][1], acc[ni]);
  }
  int trow = w * 16 + (lane >> 4) * 4;
#pragma unroll
  for (int ni = 0; ni < 4; ++ni)
#pragma unroll
    for (int r = 0; r < 4; ++r) {
      int t = trow + r;
      int s = ni * 16 + (lane & 15);
      float v = (s <= t) ? acc[ni][r] : 0.f;
      Ag[(size_t)bc * 4096 + t * 64 + s] = f2bf(v);
    }
}

// ---------------- chunk state build: hloc[bc][di][k] = sum_s ktEt[k,s] * Vt[di,s] ----------------
// grid (DI/64, NC, B), 256 thr
__global__ __launch_bounds__(256) void hlocB_kernel(const bf16* __restrict__ Vt,
    const bf16* __restrict__ ktEt, bf16* __restrict__ hloc) {
  int tid = threadIdx.x, lane = tid & 63, w = tid >> 6;
  int dt = blockIdx.x, c = blockIdx.y, b = blockIdx.z;
  int bc = b * NC_ + c;
  int di0 = dt * 64;
  f32x4 acc[4] = {};
  bf16x8 xv[2], yk[4][2];
#pragma unroll
  for (int ks = 0; ks < 2; ++ks)
    xv[ks] = *(const bf16x8*)(Vt + ((size_t)b * DI_ + di0 + w * 16 + (lane & 15)) * T_ + c * 64 + ks * 32 + (lane >> 4) * 8);
#pragma unroll
  for (int ni = 0; ni < 4; ++ni)
#pragma unroll
    for (int ks = 0; ks < 2; ++ks)
      yk[ni][ks] = *(const bf16x8*)(ktEt + ((size_t)bc * 64 + ni * 16 + (lane & 15)) * 64 + ks * 32 + (lane >> 4) * 8);
#pragma unroll
  for (int ni = 0; ni < 4; ++ni) {
    acc[ni] = mfma16(xv[0], yk[ni][0], acc[ni]);
    acc[ni] = mfma16(xv[1], yk[ni][1], acc[ni]);
  }
  int dirow = di0 + w * 16 + (lane >> 4) * 4;
#pragma unroll
  for (int ni = 0; ni < 4; ++ni)
#pragma unroll
    for (int r = 0; r < 4; ++r)
      hloc[((size_t)bc * DI_ + dirow + r) * 64 + ni * 16 + (lane & 15)] = f2bf(acc[ni][r]);
}

// ---------------- cross-chunk state combine (di-major, in-place -> h_in) ----------------
__global__ void combine_kernel(bf16* __restrict__ h, const float* __restrict__ Dtot) {
  int tid = threadIdx.x;
  int k = tid & 63;
  int di = blockIdx.x * 4 + (tid >> 6);
  int b = blockIdx.y;
  float run = 0.f;
#pragma unroll
  for (int c = 0; c < NC_; ++c) {
    size_t idx = ((size_t)((b * NC_ + c)) * DI_ + di) * 64 + k;
    float t = bf2f(h[idx]);
    h[idx] = f2bf(run);
    run = run * Dtot[(b * NC_ + c) * 64 + k] + t;
  }
}

// ---------------- fused output: o = A @ V + qhat2 @ h_in ----------------
// grid (DI/64, NC, B), 256 thr; all operands k-contiguous from global, no LDS
__global__ __launch_bounds__(256) void fusedC_kernel(const bf16* __restrict__ Ag,
    const bf16* __restrict__ qhat2, const bf16* __restrict__ Vt,
    const bf16* __restrict__ hin, bf16* __restrict__ o) {
  int tid = threadIdx.x, lane = tid & 63, w = tid >> 6;
  int dt = blockIdx.x, c = blockIdx.y, b = blockIdx.z;
  int bc = b * NC_ + c;
  int di0 = dt * 64;
  size_t row0 = (size_t)b * T_ + c * 64;
  f32x4 acc[4] = {};
  bf16x8 aA[2], aq[2], yv[4][2], yh[4][2];
#pragma unroll
  for (int ks = 0; ks < 2; ++ks) {
    aA[ks] = *(const bf16x8*)(Ag + (size_t)bc * 4096 + (w * 16 + (lane & 15)) * 64 + ks * 32 + (lane >> 4) * 8);
    aq[ks] = *(const bf16x8*)(qhat2 + (row0 + w * 16 + (lane & 15)) * 64 + ks * 32 + (lane >> 4) * 8);
  }
#pragma unroll
  for (int ni = 0; ni < 4; ++ni)
#pragma unroll
    for (int ks = 0; ks < 2; ++ks) {
      yv[ni][ks] = *(const bf16x8*)(Vt + ((size_t)b * DI_ + di0 + ni * 16 + (lane & 15)) * T_ + c * 64 + ks * 32 + (lane >> 4) * 8);
      yh[ni][ks] = *(const bf16x8*)(hin + ((size_t)bc * DI_ + di0 + ni * 16 + (lane & 15)) * 64 + ks * 32 + (lane >> 4) * 8);
    }
#pragma unroll
  for (int ni = 0; ni < 4; ++ni) {
    acc[ni] = mfma16(aA[0], yv[ni][0], acc[ni]);
    acc[ni] = mfma16(aA[1], yv[ni][1], acc[ni]);
    acc[ni] = mfma16(aq[0], yh[ni][0], acc[ni]);
    acc[ni] = mfma16(aq[1], yh[ni][1], acc[ni]);
  }
  int trow = w * 16 + (lane >> 4) * 4;
#pragma unroll
  for (int ni = 0; ni < 4; ++ni)
#pragma unroll
    for (int r = 0; r < 4; ++r)
      o[(row0 + trow + r) * DI_ + di0 + ni * 16 + (lane & 15)] = f2bf(acc[ni][r]);
}

// ---------------- residual + gated RMSNorm (in-place on o) ----------------
__global__ __launch_bounds__(256) void norm_kernel(bf16* o_io,
    const bf16* __restrict__ shf, const bf16* __restrict__ fg,
    const float* __restrict__ res_w, const float* __restrict__ norm_w) {
  __shared__ float sred[4];
  int tid = threadIdx.x;
  size_t row = blockIdx.x;
  float vals[8];
  float ss = 0.f;
#pragma unroll
  for (int j = 0; j < 8; ++j) {
    int di = tid + j * 256;
    float x2 = bf2f(o_io[row * DI_ + di]) + bf2f(shf[row * DI_ + di]) * res_w[di];
    vals[j] = x2;
    ss += x2 * x2;
  }
#pragma unroll
  for (int off = 32; off > 0; off >>= 1) ss += __shfl_xor(ss, off);
  if ((tid & 63) == 0) sred[tid >> 6] = ss;
  __syncthreads();
  float tot = sred[0] + sred[1] + sred[2] + sred[3];
  float rinv = rsqrtf(tot / DI_ + 1e-5f);
#pragma unroll
  for (int j = 0; j < 8; ++j) {
    int di = tid + j * 256;
    float fgs = 1.f / (1.f + expf(-bf2f(fg[row * DI_ + di])));
    o_io[row * DI_ + di] = f2bf(vals[j] * rinv * norm_w[di] * fgs);
  }
}

// ---------------- host launcher ----------------
// Workspace (TOTAL 177,766,400 B < proven 200,818,688):
//  front [0, 72,876,032): x_bf, wug, wqkgt, wi1p, proj, i1, hid
//    overlays: hloc @0 (33,554,432; valid after gates_cum — proj dead),
//              wdown @35,127,296 (4,194,304; after vgate_t — i1 dead),
//              o @39,321,600 (33,554,432; after vgate_t — hid dead)
//  72,876,032: Vt 33,554,432
//  106,430,464: shf 33,554,432
//  139,984,896: fgb 33,554,432
//  173,539,328: qhat2 1M | 174,587,904: kt0 1M | 175,636,480: ktEt 1M
//  176,685,056: Ag 1M | 177,733,632: Dtot 32K
extern "C" void kernel_launch(void* const* d_in, const int* in_sizes, int n_in,
                              void* d_out, int out_size, void* d_ws, size_t ws_size,
                              hipStream_t stream) {
  const float* x      = (const float*)d_in[0];
  const float* w_gate = (const float*)d_in[1];
  const float* w_up   = (const float*)d_in[2];
  const float* w_down = (const float*)d_in[3];
  const float* w_q    = (const float*)d_in[4];
  const float* w_k    = (const float*)d_in[5];
  const float* w_g    = (const float*)d_in[6];
  const float* b_g    = (const float*)d_in[7];
  const float* w_tau  = (const float*)d_in[8];
  const float* b_tau  = (const float*)d_in[9];
  const float* w_i1   = (const float*)d_in[10];
  const float* w_i2   = (const float*)d_in[11];
  const float* b_i2   = (const float*)d_in[12];
  const float* norm_w = (const float*)d_in[13];
  const float* res_w  = (const float*)d_in[14];
  float* out = (float*)d_out;

  char* base = (char*)d_ws;
  bf16*  x_bf  = (bf16*)(base + 0);
  bf16*  wug   = (bf16*)(base + 16777216);
  bf16*  wqkgt = (bf16*)(base + 25165824);
  bf16*  wi1p  = (bf16*)(base + 26214400);
  float* proj  = (float*)(base + 26738688);
  float* i1    = (float*)(base + 35127296);
  bf16*  hid   = (bf16*)(base + 39321600);
  bf16*  hloc  = (bf16*)(base + 0);            // overlay
  bf16*  wdown = (bf16*)(base + 35127296);     // overlay
  bf16*  obuf  = (bf16*)(base + 39321600);     // overlay (hid dead)
  bf16*  Vt    = (bf16*)(base + 72876032);
  bf16*  shf   = (bf16*)(base + 106430464);
  bf16*  fgb   = (bf16*)(base + 139984896);
  bf16*  qhat2 = (bf16*)(base + 173539328);
  bf16*  kt0   = (bf16*)(base + 174587904);
  bf16*  ktEt  = (bf16*)(base + 175636480);
  bf16*  Ag    = (bf16*)(base + 176685056);
  float* Dtot  = (float*)(base + 177733632);
  const size_t TOTAL = 177766400;
  if (ws_size < TOTAL) {
    fill_kernel<<<dim3(512), 256, 0, stream>>>(out, 1.0e6f, out_size);
    return;
  }

  hipFuncSetAttribute((const void*)gemm256<1>, hipFuncAttributeMaxDynamicSharedMemorySize, 131072);
  hipFuncSetAttribute((const void*)gemm256<2>, hipFuncAttributeMaxDynamicSharedMemorySize, 131072);

  // zero split-K accumulators (+ d_out for GEMM4 atomics)
  hipMemsetAsync(proj, 0, (size_t)BT_ * 256 * 4, stream);
  hipMemsetAsync(i1, 0, (size_t)BT_ * 128 * 4, stream);
  hipMemsetAsync(out, 0, (size_t)out_size * 4, stream);

  fused_cast_kernel<<<dim3(2048), 256, 0, stream>>>(x, w_up, w_gate, w_q, w_k, w_g, w_tau, w_i1,
                                                    x_bf, wug, wqkgt, wi1p);

  // GEMM1: [hid|fg] = x @ [w_up;w_gate]^T + SiLU  (grid 512)
  gemm256<1><<<dim3(512, 1), 512, 131072, stream>>>(x_bf, wug, H_, H_, 4096, 16, nullptr, hid, shf, fgb);
  // GEMM2: proj = shf @ [wq;wk;wg;wtau]^T  (split-K x4, atomic)
  gemm_bt<1><<<dim3(2, 64, 4), 256, 0, stream>>>(shf, wqkgt, DI_, 256, 512, proj);
  // GEMM3: i1 = hid @ w_i1p^T  (split-K x8, atomic)
  gemm_bt<1><<<dim3(1, 64, 8), 256, 0, stream>>>(hid, wi1p, DI_, 128, 256, i1);

  gates_cum_kernel<<<dim3(B_ * NC_), 256, 0, stream>>>(proj, b_g, b_tau, qhat2, kt0, ktEt, Dtot);
  vgate_t_kernel<<<dim3(T_ / 64, DI_ / 64, B_), 256, 0, stream>>>(hid, i1, w_i2, b_i2, Vt);
  // front dead -> overlays valid
  cast_kernel<<<dim3(512), 256, 0, stream>>>(w_down, wdown, H_ * DI_);

  intraA_kernel<<<dim3(B_ * NC_), 256, 0, stream>>>(qhat2, kt0, Ag);
  hlocB_kernel<<<dim3(DI_ / 64, NC_, B_), 256, 0, stream>>>(Vt, ktEt, hloc);
  combine_kernel<<<dim3(512, B_), 256, 0, stream>>>(hloc, Dtot);
  fusedC_kernel<<<dim3(DI_ / 64, NC_, B_), 256, 0, stream>>>(Ag, qhat2, Vt, hloc, obuf);

  norm_kernel<<<dim3(BT_), 256, 0, stream>>>(obuf, shf, fgb, res_w, norm_w);
  // GEMM4: out = o @ w_down^T  (split-K x2 atomic, grid 128x2 -> 256 blocks)
  gemm256<2><<<dim3(128, 2), 512, 131072, stream>>>(obuf, wdown, 1024, DI_, H_, 4, out, nullptr, nullptr, nullptr);
}

// Round 6
// 537.886 us; speedup vs baseline: 1.2833x; 1.0460x over previous
//
#include <hip/hip_runtime.h>
#include <hip/hip_bf16.h>
#include <math.h>

using bf16 = __hip_bfloat16;
typedef __attribute__((ext_vector_type(8))) short bf16x8;
typedef __attribute__((ext_vector_type(4))) float f32x4;

#define B_ 4
#define T_ 2048
#define H_ 1024
#define DI_ 2048
#define BT_ 8192
#define NC_ 32
#define CHUNK_ 64

__device__ __forceinline__ float bf2f(bf16 x) { return __bfloat162float(x); }
__device__ __forceinline__ bf16 f2bf(float x) { return __float2bfloat16(x); }
__device__ __forceinline__ float sigmf(float z) { return 1.f / (1.f + __expf(-z)); }
__device__ __forceinline__ f32x4 mfma16(bf16x8 a, bf16x8 b, f32x4 c) {
  return __builtin_amdgcn_mfma_f32_16x16x32_bf16(a, b, c, 0, 0, 0);
}
__device__ __forceinline__ void gload_lds16(const bf16* g, bf16* l) {
  __builtin_amdgcn_global_load_lds((const __attribute__((address_space(1))) void*)(g),
                                   (__attribute__((address_space(3))) void*)(l), 16, 0, 0);
}
// LDS XOR-swizzle for 128B-row tiles (involution: bits 4-6 ^= row bits 0-2)
__device__ __forceinline__ int swzb(int x) { return x ^ (((x >> 7) & 7) << 4); }

// ---------------- cast kernels ----------------
__global__ void cast_kernel(const float* __restrict__ in, bf16* __restrict__ out, int n) {
  int i = blockIdx.x * 256 + threadIdx.x;
  int stride = gridDim.x * 256;
  for (; i < n; i += stride) out[i] = f2bf(in[i]);
}

struct bf16q { bf16 a, b, c, d; };
__device__ __forceinline__ void cast4(const float* __restrict__ src, bf16* __restrict__ dst, int q) {
  float4 v = *(const float4*)(src + (size_t)q * 4);
  bf16q t = { f2bf(v.x), f2bf(v.y), f2bf(v.z), f2bf(v.w) };
  *(bf16q*)(dst + (size_t)q * 4) = t;
}

__global__ void fused_cast_kernel(const float* __restrict__ x, const float* __restrict__ w_up,
                                  const float* __restrict__ w_gate, const float* __restrict__ w_q,
                                  const float* __restrict__ w_k, const float* __restrict__ w_g,
                                  const float* __restrict__ w_tau, const float* __restrict__ w_i1,
                                  bf16* __restrict__ x_bf, bf16* __restrict__ wug,
                                  bf16* __restrict__ wqkgt, bf16* __restrict__ wi1p) {
  const int B1 = 2097152;      // x quads
  const int B2 = 2621440;      // + w_up
  const int B3 = 3145728;      // + w_gate
  const int B4 = 3178496;      // + w_q
  const int B5 = 3211264;      // + w_k
  const int B6 = 3244032;      // + w_g
  const int B7 = 3276800;      // + w_tau
  const int END = 3342336;     // + wi1p (pad)
  int i = blockIdx.x * 256 + threadIdx.x;
  int stride = gridDim.x * 256;
  for (; i < END; i += stride) {
    if (i < B1)      cast4(x,      x_bf,                i);
    else if (i < B2) cast4(w_up,   wug,                 i - B1);
    else if (i < B3) cast4(w_gate, wug + 2097152,       i - B2);
    else if (i < B4) cast4(w_q,    wqkgt,               i - B3);
    else if (i < B5) cast4(w_k,    wqkgt + 131072,      i - B4);
    else if (i < B6) cast4(w_g,    wqkgt + 262144,      i - B5);
    else if (i < B7) cast4(w_tau,  wqkgt + 393216,      i - B6);
    else {
      int q = i - B7;
      if (q < 8192) cast4(w_i1, wi1p, q);
      else { bf16q z = { f2bf(0.f), f2bf(0.f), f2bf(0.f), f2bf(0.f) }; *(bf16q*)(wi1p + (size_t)q * 4) = z; }
    }
  }
}

__global__ void fill_kernel(float* __restrict__ out, float v, int n) {
  int i = blockIdx.x * 256 + threadIdx.x;
  int stride = gridDim.x * 256;
  for (; i < n; i += stride) out[i] = v;
}

// ============ 256x256-tile 8-phase bf16 GEMM (T1+T2+T3+T4+T5) ============
// EPI 0: fp32 store. EPI 1: hid/shf/fg epilogue. EPI 2: atomic fp32 (split-K via blockIdx.y).
template <int EPI>
__global__ __launch_bounds__(512) void gemm256(
    const bf16* __restrict__ A, const bf16* __restrict__ Bw, int K, int kstride, int N, int NBN,
    float* __restrict__ Cf, bf16* __restrict__ hid, bf16* __restrict__ shf, bf16* __restrict__ fg) {
  extern __shared__ bf16 lds[];
  bf16* As = lds;
  bf16* Bs = lds + 32768;
  const int tid = threadIdx.x;
  const int lane = tid & 63;
  const int wv = tid >> 6;
  const int wr = wv >> 2;
  const int wc = wv & 3;
  const int cpx = gridDim.x >> 3;
  const int bid = blockIdx.x;
  const int swz = (bid & 7) * cpx + (bid >> 3);
  const int bm = swz / NBN, bn = swz % NBN;
  const size_t arow0 = (size_t)bm * 256;
  const size_t brow0 = (size_t)bn * 256;
  const int koff = blockIdx.y * K;

  const bf16* gA[2][2]; const bf16* gB[2][2];
  int loff[2][2];
#pragma unroll
  for (int h = 0; h < 2; ++h)
#pragma unroll
    for (int j = 0; j < 2; ++j) {
      int D = h * 16384 + (j * 512 + tid) * 16;   // phys byte (linear gload dest)
      int L = swzb(D);                            // logical byte (involution)
      int lrow = L >> 7;
      int col = (L & 127) >> 1;
      int arow = ((lrow >> 6) & 1) * 128 + h * 64 + (lrow & 63);
      int lrl = lrow & 127;
      int brow = (lrl >> 5) * 64 + h * 32 + (lrl & 31);
      gA[h][j] = A + (arow0 + arow) * (size_t)kstride + koff + col;
      gB[h][j] = Bw + (brow0 + brow) * (size_t)kstride + koff + col;
      loff[h][j] = D >> 1;
    }
#define STAGE_A(buf, h, kt) { gload_lds16(gA[h][0] + (kt), As + (buf) * 16384 + loff[h][0]); \
                              gload_lds16(gA[h][1] + (kt), As + (buf) * 16384 + loff[h][1]); }
#define STAGE_B(buf, h, kt) { gload_lds16(gB[h][0] + (kt), Bs + (buf) * 16384 + loff[h][0]); \
                              gload_lds16(gB[h][1] + (kt), Bs + (buf) * 16384 + loff[h][1]); }

  auto lda = [&](int buf, int mh, int mi, int ks) -> bf16x8 {
    int lrow = (mh * 2 + wr) * 64 + mi * 16 + (lane & 15);
    int byte = swzb(lrow * 128 + ks * 64 + (lane >> 4) * 16);
    return *(const bf16x8*)&As[buf * 16384 + (byte >> 1)];
  };
  auto ldb = [&](int buf, int nh, int ni, int ks) -> bf16x8 {
    int lrow = (nh * 4 + wc) * 32 + ni * 16 + (lane & 15);
    int byte = swzb(lrow * 128 + ks * 64 + (lane >> 4) * 16);
    return *(const bf16x8*)&Bs[buf * 16384 + (byte >> 1)];
  };

  f32x4 acc[8][4] = {};
  const int NT = K >> 6;
  STAGE_A(0, 0, 0); STAGE_B(0, 0, 0); STAGE_A(0, 1, 0); STAGE_B(0, 1, 0);
  if (NT > 1) { STAGE_A(1, 0, 64); STAGE_B(1, 0, 64); }
  asm volatile("s_waitcnt vmcnt(4)" ::: "memory");
  __syncthreads();

  for (int t = 0; t < NT; ++t) {
    const int cur = t & 1, nxt = cur ^ 1;
    const int kt1 = (t + 1) << 6, kt2 = (t + 2) << 6;
    bf16x8 a0[4][2], a1[4][2], b0[2][2], b1[2][2];
    // ---- phase 1 ----
#pragma unroll
    for (int mi = 0; mi < 4; ++mi) { a0[mi][0] = lda(cur, 0, mi, 0); a0[mi][1] = lda(cur, 0, mi, 1); }
#pragma unroll
    for (int ni = 0; ni < 2; ++ni) { b0[ni][0] = ldb(cur, 0, ni, 0); b0[ni][1] = ldb(cur, 0, ni, 1); }
    if (t + 1 < NT) STAGE_A(nxt, 1, kt1);
    __builtin_amdgcn_s_barrier();
    asm volatile("s_waitcnt lgkmcnt(0)" ::: "memory");
    __builtin_amdgcn_sched_barrier(0);
    __builtin_amdgcn_s_setprio(1);
#pragma unroll
    for (int mi = 0; mi < 4; ++mi)
#pragma unroll
      for (int ni = 0; ni < 2; ++ni) {
        acc[mi][ni] = mfma16(a0[mi][0], b0[ni][0], acc[mi][ni]);
        acc[mi][ni] = mfma16(a0[mi][1], b0[ni][1], acc[mi][ni]);
      }
    __builtin_amdgcn_s_setprio(0);
    __builtin_amdgcn_s_barrier();
    // ---- phase 2 ----
#pragma unroll
    for (int ni = 0; ni < 2; ++ni) { b1[ni][0] = ldb(cur, 1, ni, 0); b1[ni][1] = ldb(cur, 1, ni, 1); }
    if (t + 1 < NT) STAGE_B(nxt, 1, kt1);
    __builtin_amdgcn_s_barrier();
    asm volatile("s_waitcnt lgkmcnt(0)" ::: "memory");
    __builtin_amdgcn_sched_barrier(0);
    __builtin_amdgcn_s_setprio(1);
#pragma unroll
    for (int mi = 0; mi < 4; ++mi)
#pragma unroll
      for (int ni = 0; ni < 2; ++ni) {
        acc[mi][2 + ni] = mfma16(a0[mi][0], b1[ni][0], acc[mi][2 + ni]);
        acc[mi][2 + ni] = mfma16(a0[mi][1], b1[ni][1], acc[mi][2 + ni]);
      }
    __builtin_amdgcn_s_setprio(0);
    __builtin_amdgcn_s_barrier();
    // ---- phase 3 ----
#pragma unroll
    for (int mi = 0; mi < 4; ++mi) { a1[mi][0] = lda(cur, 1, mi, 0); a1[mi][1] = lda(cur, 1, mi, 1); }
    if (t + 2 < NT) STAGE_A(cur, 0, kt2);
    __builtin_amdgcn_s_barrier();
    asm volatile("s_waitcnt lgkmcnt(0)" ::: "memory");
    __builtin_amdgcn_sched_barrier(0);
    __builtin_amdgcn_s_setprio(1);
#pragma unroll
    for (int mi = 0; mi < 4; ++mi)
#pragma unroll
      for (int ni = 0; ni < 2; ++ni) {
        acc[4 + mi][ni] = mfma16(a1[mi][0], b0[ni][0], acc[4 + mi][ni]);
        acc[4 + mi][ni] = mfma16(a1[mi][1], b0[ni][1], acc[4 + mi][ni]);
      }
    __builtin_amdgcn_s_setprio(0);
    __builtin_amdgcn_s_barrier();
    // ---- phase 4 ----
    if (t + 2 < NT) STAGE_B(cur, 0, kt2);
    __builtin_amdgcn_s_barrier();
    __builtin_amdgcn_s_setprio(1);
#pragma unroll
    for (int mi = 0; mi < 4; ++mi)
#pragma unroll
      for (int ni = 0; ni < 2; ++ni) {
        acc[4 + mi][2 + ni] = mfma16(a1[mi][0], b1[ni][0], acc[4 + mi][2 + ni]);
        acc[4 + mi][2 + ni] = mfma16(a1[mi][1], b1[ni][1], acc[4 + mi][2 + ni]);
      }
    __builtin_amdgcn_s_setprio(0);
    if (t < NT - 2) { asm volatile("s_waitcnt vmcnt(4)" ::: "memory"); }
    else            { asm volatile("s_waitcnt vmcnt(0)" ::: "memory"); }
    __builtin_amdgcn_s_barrier();
  }

  const int r0 = wr * 128 + (lane >> 4) * 4;
  const int c0 = wc * 64 + (lane & 15);
#pragma unroll
  for (int mi = 0; mi < 8; ++mi)
#pragma unroll
    for (int ni = 0; ni < 4; ++ni)
#pragma unroll
      for (int r = 0; r < 4; ++r) {
        size_t row = arow0 + r0 + mi * 16 + r;
        int col = (int)brow0 + c0 + ni * 16;
        float v = acc[mi][ni][r];
        if (EPI == 0) {
          Cf[row * (size_t)N + col] = v;
        } else if (EPI == 2) {
          atomicAdd(&Cf[row * (size_t)N + col], v);
        } else {
          if (col < DI_) {
            hid[row * DI_ + col] = f2bf(v);
            shf[row * DI_ + col] = f2bf(v * sigmf(v));
          } else {
            fg[row * DI_ + (col - DI_)] = f2bf(v);
          }
        }
      }
#undef STAGE_A
#undef STAGE_B
}

// ---------------- 2-phase 128x128 GEMM with split-K atomic epilogue ----------------
template <int ATOMIC>
__global__ __launch_bounds__(256) void gemm_bt(
    const bf16* __restrict__ A, const bf16* __restrict__ Bw, int K, int N, int kchunk,
    float* __restrict__ Cf) {
  __shared__ bf16 As[128 * 64];
  __shared__ bf16 Bs[128 * 64];
  const int tid = threadIdx.x;
  const int lane = tid & 63;
  const int wave = tid >> 6;
  const int bn = blockIdx.x, bm = blockIdx.y;
  const int wr = (wave >> 1) * 64, wc = (wave & 1) * 64;
  f32x4 acc[4][4] = {};
  const int srow = tid >> 3;
  const int scol = (tid & 7) * 8;
  const size_t arow0 = (size_t)bm * 128;
  const size_t brow0 = (size_t)bn * 128;
  const int k0 = blockIdx.z * kchunk;

  for (int kt = k0; kt < k0 + kchunk; kt += 64) {
#pragma unroll
    for (int i = 0; i < 4; ++i) {
      const bf16* ga = A + (arow0 + i * 32 + srow) * (size_t)K + kt + scol;
      const bf16* gb = Bw + (brow0 + i * 32 + srow) * (size_t)K + kt + scol;
      gload_lds16(ga, &As[(i * 32 + srow) * 64 + scol]);
      gload_lds16(gb, &Bs[(i * 32 + srow) * 64 + scol]);
    }
    asm volatile("s_waitcnt vmcnt(0)" ::: "memory");
    __syncthreads();
#pragma unroll
    for (int ks = 0; ks < 64; ks += 32) {
      bf16x8 af[4], bfr[4];
#pragma unroll
      for (int i = 0; i < 4; ++i) {
        af[i]  = *(const bf16x8*)&As[(wr + i * 16 + (lane & 15)) * 64 + ks + (lane >> 4) * 8];
        bfr[i] = *(const bf16x8*)&Bs[(wc + i * 16 + (lane & 15)) * 64 + ks + (lane >> 4) * 8];
      }
#pragma unroll
      for (int i = 0; i < 4; ++i)
#pragma unroll
        for (int j = 0; j < 4; ++j)
          acc[i][j] = mfma16(af[i], bfr[j], acc[i][j]);
    }
    __syncthreads();
  }

  const int crow = wr + (lane >> 4) * 4;
  const int ccol = wc + (lane & 15);
#pragma unroll
  for (int i = 0; i < 4; ++i)
#pragma unroll
    for (int j = 0; j < 4; ++j)
#pragma unroll
      for (int r = 0; r < 4; ++r) {
        size_t row = arow0 + crow + i * 16 + r;
        int col = (int)brow0 + ccol + j * 16;
        float v = acc[i][j][r];
        if (ATOMIC) atomicAdd(&Cf[row * (size_t)N + col], v);
        else Cf[row * (size_t)N + col] = v;
      }
}

// ---------------- fused gates + chunk-cumsum -> bounded bf16 decay factors ----------------
__global__ __launch_bounds__(256) void gates_cum_kernel(const float* __restrict__ proj,
    const float* __restrict__ b_g, const float* __restrict__ b_tau,
    bf16* __restrict__ qhat2, bf16* __restrict__ kt0, bf16* __restrict__ ktEt,
    float* __restrict__ Dtot) {
  __shared__ float s_gk[64 * 64];   // gkv, then gc
  __shared__ float s_kh[64 * 64];   // khat
  __shared__ float segsum[4 * 64];
  int tid = threadIdx.x;
  int lane = tid & 63;
  int wvv = tid >> 6;
  int bc = blockIdx.x;
  size_t row0 = (size_t)((bc >> 5) * T_ + (bc & 31) * CHUNK_);
  for (int r = wvv; r < CHUNK_; r += 4) {
    const float* p = proj + (row0 + r) * 256;
    float kk = p[64 + lane];
    float zg = p[128 + lane] + b_g[lane];
    float zt = p[192 + lane] + b_tau[lane];
    float gg  = (zg > 20.f) ? zg : log1pf(__expf(zg));
    float tau = sigmf(zt);
    float it  = __powf(gg, tau);
    float gkv = -gg * tau;
    float s = kk * kk;
#pragma unroll
    for (int off = 32; off > 0; off >>= 1) s += __shfl_xor(s, off);
    float kn = sqrtf(s);
    s_kh[r * 64 + lane] = kk / fmaxf(kn, 1e-12f) * it;
    s_gk[r * 64 + lane] = gkv;
  }
  __syncthreads();
  float loc = 0.f;
  for (int r = wvv * 16; r < wvv * 16 + 16; ++r) loc += s_gk[r * 64 + lane];
  segsum[wvv * 64 + lane] = loc;
  __syncthreads();
  float gc = 0.f;
  for (int ss = 0; ss < wvv; ++ss) gc += segsum[ss * 64 + lane];
  for (int r = wvv * 16; r < wvv * 16 + 16; ++r) {
    gc += s_gk[r * 64 + lane];
    float qv = proj[(row0 + r) * 256 + lane] * 0.125f;
    qhat2[(row0 + r) * 64 + lane] = f2bf(qv * __expf(gc));
    s_gk[r * 64 + lane] = gc;
  }
  __syncthreads();
  float gcend = s_gk[63 * 64 + lane];
  for (int r = wvv; r < CHUNK_; r += 4) {
    float gcr = s_gk[r * 64 + lane];
    float kh  = s_kh[r * 64 + lane];
    kt0[(row0 + r) * 64 + lane] = f2bf(kh * __expf(-gcr));
    ktEt[((size_t)bc * 64 + lane) * 64 + r] = f2bf(kh * __expf(gcend - gcr));
  }
  if (tid < 64) Dtot[bc * 64 + tid] = __expf(s_gk[63 * 64 + tid]);
}

// ---------------- v-gate fused with transpose: Vt[b][di][t] ----------------
__global__ __launch_bounds__(256) void vgate_t_kernel(const bf16* __restrict__ hid,
    const float* __restrict__ i1, const float* __restrict__ w_i2, const float* __restrict__ b_i2,
    bf16* __restrict__ Vt) {
  __shared__ float s_w2[16 * 64];
  __shared__ bf16 tile[64][65];
  int tid = threadIdx.x;
  int tt = blockIdx.x, dt = blockIdx.y, b = blockIdx.z;
  int di0 = dt * 64;
  size_t row0 = (size_t)b * T_ + tt * 64;
  {
    int d = tid & 63, l4 = tid >> 6;
#pragma unroll
    for (int l = l4 * 4; l < l4 * 4 + 4; ++l)
      s_w2[l * 64 + d] = w_i2[(size_t)(di0 + d) * 16 + l];
  }
  __syncthreads();
  {
    int d = tid & 63, rb = tid >> 6;
    float bi = b_i2[di0 + d];
    for (int j = 0; j < 16; ++j) {
      int r = rb + 4 * j;
      const float* ip = &i1[(row0 + r) * 128];
      float z = bi;
#pragma unroll
      for (int l = 0; l < 16; ++l) z += ip[l] * s_w2[l * 64 + d];
      float hv = bf2f(hid[(row0 + r) * DI_ + di0 + d]);
      tile[d][r] = f2bf(hv * sigmf(z));
    }
  }
  __syncthreads();
  {
    int t = tid & 63, db = tid >> 6;
    for (int j = 0; j < 16; ++j) {
      int d = db + 4 * j;
      Vt[((size_t)b * DI_ + di0 + d) * T_ + tt * 64 + t] = tile[d][t];
    }
  }
}

// ---------------- intra-chunk score matrix: A = tril(qhat2 @ kt0^T), bf16 ----------------
__global__ __launch_bounds__(256) void intraA_kernel(const bf16* __restrict__ qhat2,
    const bf16* __restrict__ kt0, bf16* __restrict__ Ag) {
  int tid = threadIdx.x, lane = tid & 63, w = tid >> 6;
  int bc = blockIdx.x;
  size_t row0 = (size_t)((bc >> 5) * T_ + (bc & 31) * CHUNK_);
  f32x4 acc[4] = {};
  bf16x8 a[2], y[4][2];
#pragma unroll
  for (int ks = 0; ks < 2; ++ks)
    a[ks] = *(const bf16x8*)(qhat2 + (row0 + w * 16 + (lane & 15)) * 64 + ks * 32 + (lane >> 4) * 8);
#pragma unroll
  for (int ni = 0; ni < 4; ++ni)
#pragma unroll
    for (int ks = 0; ks < 2; ++ks)
      y[ni][ks] = *(const bf16x8*)(kt0 + (row0 + ni * 16 + (lane & 15)) * 64 + ks * 32 + (lane >> 4) * 8);
#pragma unroll
  for (int ni = 0; ni < 4; ++ni) {
    acc[ni] = mfma16(a[0], y[ni][0], acc[ni]);
    acc[ni] = mfma16(a[1], y[ni][1], acc[ni]);
  }
  int trow = w * 16 + (lane >> 4) * 4;
#pragma unroll
  for (int ni = 0; ni < 4; ++ni)
#pragma unroll
    for (int r = 0; r < 4; ++r) {
      int t = trow + r;
      int s = ni * 16 + (lane & 15);
      float v = (s <= t) ? acc[ni][r] : 0.f;
      Ag[(size_t)bc * 4096 + t * 64 + s] = f2bf(v);
    }
}

// ---------------- chunk state build: hloc[bc][di][k] = sum_s ktEt[k,s] * Vt[di,s] ----------------
__global__ __launch_bounds__(256) void hlocB_kernel(const bf16* __restrict__ Vt,
    const bf16* __restrict__ ktEt, bf16* __restrict__ hloc) {
  int tid = threadIdx.x, lane = tid & 63, w = tid >> 6;
  int dt = blockIdx.x, c = blockIdx.y, b = blockIdx.z;
  int bc = b * NC_ + c;
  int di0 = dt * 64;
  f32x4 acc[4] = {};
  bf16x8 xv[2], yk[4][2];
#pragma unroll
  for (int ks = 0; ks < 2; ++ks)
    xv[ks] = *(const bf16x8*)(Vt + ((size_t)b * DI_ + di0 + w * 16 + (lane & 15)) * T_ + c * 64 + ks * 32 + (lane >> 4) * 8);
#pragma unroll
  for (int ni = 0; ni < 4; ++ni)
#pragma unroll
    for (int ks = 0; ks < 2; ++ks)
      yk[ni][ks] = *(const bf16x8*)(ktEt + ((size_t)bc * 64 + ni * 16 + (lane & 15)) * 64 + ks * 32 + (lane >> 4) * 8);
#pragma unroll
  for (int ni = 0; ni < 4; ++ni) {
    acc[ni] = mfma16(xv[0], yk[ni][0], acc[ni]);
    acc[ni] = mfma16(xv[1], yk[ni][1], acc[ni]);
  }
  int dirow = di0 + w * 16 + (lane >> 4) * 4;
#pragma unroll
  for (int ni = 0; ni < 4; ++ni)
#pragma unroll
    for (int r = 0; r < 4; ++r)
      hloc[((size_t)bc * DI_ + dirow + r) * 64 + ni * 16 + (lane & 15)] = f2bf(acc[ni][r]);
}

// ---------------- cross-chunk state combine (di-major, in-place -> h_in) ----------------
__global__ void combine_kernel(bf16* __restrict__ h, const float* __restrict__ Dtot) {
  int tid = threadIdx.x;
  int k = tid & 63;
  int di = blockIdx.x * 4 + (tid >> 6);
  int b = blockIdx.y;
  float run = 0.f;
#pragma unroll
  for (int c = 0; c < NC_; ++c) {
    size_t idx = ((size_t)((b * NC_ + c)) * DI_ + di) * 64 + k;
    float t = bf2f(h[idx]);
    h[idx] = f2bf(run);
    run = run * Dtot[(b * NC_ + c) * 64 + k] + t;
  }
}

// ---------------- fused output: o = A @ V + qhat2 @ h_in ----------------
__global__ __launch_bounds__(256) void fusedC_kernel(const bf16* __restrict__ Ag,
    const bf16* __restrict__ qhat2, const bf16* __restrict__ Vt,
    const bf16* __restrict__ hin, bf16* __restrict__ o) {
  int tid = threadIdx.x, lane = tid & 63, w = tid >> 6;
  int dt = blockIdx.x, c = blockIdx.y, b = blockIdx.z;
  int bc = b * NC_ + c;
  int di0 = dt * 64;
  size_t row0 = (size_t)b * T_ + c * 64;
  f32x4 acc[4] = {};
  bf16x8 aA[2], aq[2], yv[4][2], yh[4][2];
#pragma unroll
  for (int ks = 0; ks < 2; ++ks) {
    aA[ks] = *(const bf16x8*)(Ag + (size_t)bc * 4096 + (w * 16 + (lane & 15)) * 64 + ks * 32 + (lane >> 4) * 8);
    aq[ks] = *(const bf16x8*)(qhat2 + (row0 + w * 16 + (lane & 15)) * 64 + ks * 32 + (lane >> 4) * 8);
  }
#pragma unroll
  for (int ni = 0; ni < 4; ++ni)
#pragma unroll
    for (int ks = 0; ks < 2; ++ks) {
      yv[ni][ks] = *(const bf16x8*)(Vt + ((size_t)b * DI_ + di0 + ni * 16 + (lane & 15)) * T_ + c * 64 + ks * 32 + (lane >> 4) * 8);
      yh[ni][ks] = *(const bf16x8*)(hin + ((size_t)bc * DI_ + di0 + ni * 16 + (lane & 15)) * 64 + ks * 32 + (lane >> 4) * 8);
    }
#pragma unroll
  for (int ni = 0; ni < 4; ++ni) {
    acc[ni] = mfma16(aA[0], yv[ni][0], acc[ni]);
    acc[ni] = mfma16(aA[1], yv[ni][1], acc[ni]);
    acc[ni] = mfma16(aq[0], yh[ni][0], acc[ni]);
    acc[ni] = mfma16(aq[1], yh[ni][1], acc[ni]);
  }
  int trow = w * 16 + (lane >> 4) * 4;
#pragma unroll
  for (int ni = 0; ni < 4; ++ni)
#pragma unroll
    for (int r = 0; r < 4; ++r)
      o[(row0 + trow + r) * DI_ + di0 + ni * 16 + (lane & 15)] = f2bf(acc[ni][r]);
}

// ---------------- residual + gated RMSNorm (in-place on o) ----------------
__global__ __launch_bounds__(256) void norm_kernel(bf16* o_io,
    const bf16* __restrict__ shf, const bf16* __restrict__ fg,
    const float* __restrict__ res_w, const float* __restrict__ norm_w) {
  __shared__ float sred[4];
  int tid = threadIdx.x;
  size_t row = blockIdx.x;
  float vals[8];
  float ss = 0.f;
#pragma unroll
  for (int j = 0; j < 8; ++j) {
    int di = tid + j * 256;
    float x2 = bf2f(o_io[row * DI_ + di]) + bf2f(shf[row * DI_ + di]) * res_w[di];
    vals[j] = x2;
    ss += x2 * x2;
  }
#pragma unroll
  for (int off = 32; off > 0; off >>= 1) ss += __shfl_xor(ss, off);
  if ((tid & 63) == 0) sred[tid >> 6] = ss;
  __syncthreads();
  float tot = sred[0] + sred[1] + sred[2] + sred[3];
  float rinv = rsqrtf(tot / DI_ + 1e-5f);
#pragma unroll
  for (int j = 0; j < 8; ++j) {
    int di = tid + j * 256;
    float fgs = sigmf(bf2f(fg[row * DI_ + di]));
    o_io[row * DI_ + di] = f2bf(vals[j] * rinv * norm_w[di] * fgs);
  }
}

// ---------------- host launcher ----------------
extern "C" void kernel_launch(void* const* d_in, const int* in_sizes, int n_in,
                              void* d_out, int out_size, void* d_ws, size_t ws_size,
                              hipStream_t stream) {
  const float* x      = (const float*)d_in[0];
  const float* w_gate = (const float*)d_in[1];
  const float* w_up   = (const float*)d_in[2];
  const float* w_down = (const float*)d_in[3];
  const float* w_q    = (const float*)d_in[4];
  const float* w_k    = (const float*)d_in[5];
  const float* w_g    = (const float*)d_in[6];
  const float* b_g    = (const float*)d_in[7];
  const float* w_tau  = (const float*)d_in[8];
  const float* b_tau  = (const float*)d_in[9];
  const float* w_i1   = (const float*)d_in[10];
  const float* w_i2   = (const float*)d_in[11];
  const float* b_i2   = (const float*)d_in[12];
  const float* norm_w = (const float*)d_in[13];
  const float* res_w  = (const float*)d_in[14];
  float* out = (float*)d_out;

  char* base = (char*)d_ws;
  bf16*  x_bf  = (bf16*)(base + 0);
  bf16*  wug   = (bf16*)(base + 16777216);
  bf16*  wqkgt = (bf16*)(base + 25165824);
  bf16*  wi1p  = (bf16*)(base + 26214400);
  float* proj  = (float*)(base + 26738688);
  float* i1    = (float*)(base + 35127296);
  bf16*  hid   = (bf16*)(base + 39321600);
  bf16*  hloc  = (bf16*)(base + 0);            // overlay (after gates_cum; proj dead)
  bf16*  wdown = (bf16*)(base + 35127296);     // overlay (after vgate_t; i1 dead)
  bf16*  obuf  = (bf16*)(base + 39321600);     // overlay (hid dead)
  bf16*  Vt    = (bf16*)(base + 72876032);
  bf16*  shf   = (bf16*)(base + 106430464);
  bf16*  fgb   = (bf16*)(base + 139984896);
  bf16*  qhat2 = (bf16*)(base + 173539328);
  bf16*  kt0   = (bf16*)(base + 174587904);
  bf16*  ktEt  = (bf16*)(base + 175636480);
  bf16*  Ag    = (bf16*)(base + 176685056);
  float* Dtot  = (float*)(base + 177733632);
  const size_t TOTAL = 177766400;
  if (ws_size < TOTAL) {
    fill_kernel<<<dim3(512), 256, 0, stream>>>(out, 1.0e6f, out_size);
    return;
  }

  hipFuncSetAttribute((const void*)gemm256<1>, hipFuncAttributeMaxDynamicSharedMemorySize, 131072);
  hipFuncSetAttribute((const void*)gemm256<2>, hipFuncAttributeMaxDynamicSharedMemorySize, 131072);

  // zero split-K accumulators (proj+i1 contiguous) + d_out for GEMM4 atomics
  hipMemsetAsync(proj, 0, (size_t)BT_ * 256 * 4 + (size_t)BT_ * 128 * 4, stream);
  hipMemsetAsync(out, 0, (size_t)out_size * 4, stream);

  fused_cast_kernel<<<dim3(2048), 256, 0, stream>>>(x, w_up, w_gate, w_q, w_k, w_g, w_tau, w_i1,
                                                    x_bf, wug, wqkgt, wi1p);

  // GEMM1: [hid|fg] = x @ [w_up;w_gate]^T + SiLU
  gemm256<1><<<dim3(512, 1), 512, 131072, stream>>>(x_bf, wug, H_, H_, 4096, 16, nullptr, hid, shf, fgb);
  // GEMM2: proj = shf @ [wq;wk;wg;wtau]^T  (split-K x4, atomic)
  gemm_bt<1><<<dim3(2, 64, 4), 256, 0, stream>>>(shf, wqkgt, DI_, 256, 512, proj);
  // GEMM3: i1 = hid @ w_i1p^T  (split-K x8, atomic)
  gemm_bt<1><<<dim3(1, 64, 8), 256, 0, stream>>>(hid, wi1p, DI_, 128, 256, i1);

  gates_cum_kernel<<<dim3(B_ * NC_), 256, 0, stream>>>(proj, b_g, b_tau, qhat2, kt0, ktEt, Dtot);
  vgate_t_kernel<<<dim3(T_ / 64, DI_ / 64, B_), 256, 0, stream>>>(hid, i1, w_i2, b_i2, Vt);
  cast_kernel<<<dim3(512), 256, 0, stream>>>(w_down, wdown, H_ * DI_);

  intraA_kernel<<<dim3(B_ * NC_), 256, 0, stream>>>(qhat2, kt0, Ag);
  hlocB_kernel<<<dim3(DI_ / 64, NC_, B_), 256, 0, stream>>>(Vt, ktEt, hloc);
  combine_kernel<<<dim3(512, B_), 256, 0, stream>>>(hloc, Dtot);
  fusedC_kernel<<<dim3(DI_ / 64, NC_, B_), 256, 0, stream>>>(Ag, qhat2, Vt, hloc, obuf);

  norm_kernel<<<dim3(BT_), 256, 0, stream>>>(obuf, shf, fgb, res_w, norm_w);
  // GEMM4: out = o @ w_down^T  (split-K x2 atomic)
  gemm256<2><<<dim3(128, 2), 512, 131072, stream>>>(obuf, wdown, 1024, DI_, H_, 4, out, nullptr, nullptr, nullptr);
}